// Round 15
// baseline (257.197 us; speedup 1.0000x reference)
//
#include <hip/hip_runtime.h>

// GraphSAGE 2-layer, bf16 feature plane + MFMA GEMMs + fused dual-CSR build.
// REVERT of the round-13 experiment (setup-fusion + v_dot2 inline asm), which
// passed first-call correctness but diverged on graph-replay re-validation.
// This is the last fully-validated configuration (257 us):
//   memset+detect+init_cnt2 -> bucket2 (register-staged LDS stage-sort,
//   coalesced flush) -> csr2 (512-node-bucket counting sort) ->
//   gather_mean128 -> gemm1 -> gemmy2 -> gather_mean64 -> gemm2b.
// N=100000, E=1600000, IN=HID=128, OUT=64; edge_index int32 or int64.

#define FEAT 128
#define OUTF 64
#define BSH 9                   // 512 nodes per bucket
#define BNODES 512
#define NBMAX 256               // max buckets
#define BUCKET_BLOCKS 512       // blocks per edge-set in bucket2
#define STAGE 2048              // edges sorted+flushed per stage (8/thread)

typedef __attribute__((ext_vector_type(8))) short bf16x8;
typedef __attribute__((ext_vector_type(4))) float f32x4;

__device__ __forceinline__ unsigned f2bf_rne(float f) {
    unsigned u = __float_as_uint(f);
    return (u + 0x7fffu + ((u >> 16) & 1u)) >> 16;
}
__device__ __forceinline__ float bf_lo(unsigned u) { return __uint_as_float(u << 16); }
__device__ __forceinline__ float bf_hi(unsigned u) { return __uint_as_float(u & 0xffff0000u); }

// ---------------------------------------------------------------------------
// int64 vs int32 detection: indices < 100000 so int64 => odd 32-bit words all 0.
__global__ void detect_idx_kernel(const unsigned* __restrict__ ei, unsigned* __restrict__ flag) {
    unsigned v = ei[2 * threadIdx.x + 1];
    if (v != 0u) atomicOr(flag, 1u);
}

// ---------------------------------------------------------------------------
__global__ __launch_bounds__(256) void convert_kernel(
    const float* __restrict__ in, unsigned short* __restrict__ outb, int total4) {
    for (int i = blockIdx.x * 256 + threadIdx.x; i < total4; i += gridDim.x * 256) {
        float4 v = *(const float4*)&in[(size_t)i * 4];
        ushort4 o;
        o.x = (unsigned short)f2bf_rne(v.x);
        o.y = (unsigned short)f2bf_rne(v.y);
        o.z = (unsigned short)f2bf_rne(v.z);
        o.w = (unsigned short)f2bf_rne(v.w);
        *(ushort4*)&outb[(size_t)i * 4] = o;
    }
}

// ---------------------------------------------------------------------------
__global__ __launch_bounds__(256) void init_cnt2_kernel(
    unsigned* __restrict__ cnt1, unsigned* __restrict__ cnt2, unsigned cap, int nb) {
    int i = blockIdx.x * 256 + threadIdx.x;
    if (i < nb) { cnt1[i] = (unsigned)i * cap; cnt2[i] = (unsigned)i * cap; }
}

// ---------------------------------------------------------------------------
// Dual bucket scatter with LDS stage-sort + coalesced flush.
// Staging arrays are register-resident (static unroll); stage scan is
// wave-parallel (2 waves x 2 entries/thread over 256 histogram slots).
__global__ __launch_bounds__(256) void bucket2_kernel(
    const void* __restrict__ ei1_raw, const void* __restrict__ ei2_raw,
    unsigned* __restrict__ pairs1, unsigned* __restrict__ pairs2,
    unsigned* __restrict__ cnt1, unsigned* __restrict__ cnt2,
    const unsigned* __restrict__ flag, int e1, int e2, unsigned cap, int nb) {
    __shared__ unsigned hist[NBMAX];    // whole-chunk totals
    __shared__ unsigned wcur[NBMAX];    // global write cursor per bucket
    __shared__ unsigned lhist[NBMAX];   // per-stage hist
    __shared__ unsigned lseg[NBMAX];    // per-stage exclusive scan
    __shared__ unsigned loffs[NBMAX];   // per-stage scatter cursor
    __shared__ unsigned sorted[STAGE];
    __shared__ unsigned char sbid[STAGE];
    __shared__ unsigned wsum[2];
    const int tid = threadIdx.x;
    const int lane = tid & 63;
    const bool is32 = (*flag != 0u);
    const int side = blockIdx.x / BUCKET_BLOCKS;
    const int bid = blockIdx.x % BUCKET_BLOCKS;
    const void* ei_raw = side ? ei2_raw : ei1_raw;
    unsigned* pairs = side ? pairs2 : pairs1;
    unsigned* cnt = side ? cnt2 : cnt1;
    const int nedge = side ? e2 : e1;
    const int chunk = (nedge + BUCKET_BLOCKS - 1) / BUCKET_BLOCKS;
    const int e0 = bid * chunk;
    const int eEnd = min(e0 + chunk, nedge);
    if (e0 >= nedge) return;

    // phase 1: whole-chunk histogram
    for (int i = tid; i < nb; i += 256) hist[i] = 0u;
    __syncthreads();
    for (int e = e0 + tid; e < eEnd; e += 256) {
        int dst = is32 ? ((const int*)ei_raw)[nedge + e]
                       : (int)((const long long*)ei_raw)[nedge + e];
        atomicAdd(&hist[(unsigned)dst >> BSH], 1u);
    }
    __syncthreads();
    // phase 2: one reservation per bucket
    for (int i = tid; i < nb; i += 256) {
        unsigned c = hist[i];
        wcur[i] = c ? atomicAdd(&cnt[i], c) : 0u;
    }
    __syncthreads();

    // phase 3: staged sort + coalesced flush
    for (int s0 = e0; s0 < eEnd; s0 += STAGE) {
        const int sEnd = min(s0 + STAGE, eEnd);
        const int cs = sEnd - s0;
        for (int i = tid; i < NBMAX; i += 256) lhist[i] = 0u;
        __syncthreads();
        unsigned myp[8];
        unsigned myb[8];
        bool myv[8];
        #pragma unroll
        for (int k = 0; k < 8; ++k) {
            int e = s0 + k * 256 + tid;
            bool valid = e < sEnd;
            myv[k] = valid;
            int src = 0, dst = 0;
            if (valid) {
                if (is32) {
                    const int* ei = (const int*)ei_raw;
                    src = ei[e]; dst = ei[nedge + e];
                } else {
                    const long long* ei = (const long long*)ei_raw;
                    src = (int)ei[e]; dst = (int)ei[nedge + e];
                }
            }
            unsigned b = (unsigned)dst >> BSH;
            myp[k] = (((unsigned)dst & (BNODES - 1u)) << 17) | (unsigned)src;
            myb[k] = b;
            if (valid) atomicAdd(&lhist[b], 1u);
        }
        __syncthreads();
        // wave-parallel exclusive scan over 256 slots: threads 0..127, 2 each
        unsigned incl = 0, tsum = 0, sv0 = 0;
        if (tid < 128) {
            sv0 = lhist[2 * tid];
            unsigned sv1 = lhist[2 * tid + 1];
            tsum = sv0 + sv1;
            incl = tsum;
            #pragma unroll
            for (int off = 1; off < 64; off <<= 1) {
                unsigned t = __shfl_up(incl, off, 64);
                if (lane >= off) incl += t;
            }
            if (lane == 63) wsum[tid >> 6] = incl;
        }
        __syncthreads();
        if (tid < 128) {
            unsigned pre = (tid >> 6 ? wsum[0] : 0u) + incl - tsum;
            lseg[2 * tid] = pre;
            lseg[2 * tid + 1] = pre + sv0;
            loffs[2 * tid] = pre;
            loffs[2 * tid + 1] = pre + sv0;
        }
        __syncthreads();
        #pragma unroll
        for (int k = 0; k < 8; ++k) {
            if (myv[k]) {
                unsigned p = atomicAdd(&loffs[myb[k]], 1u);
                sorted[p] = myp[k];
                sbid[p] = (unsigned char)myb[k];
            }
        }
        __syncthreads();
        for (int i = tid; i < cs; i += 256) {
            unsigned b = sbid[i];
            unsigned pos = wcur[b] + ((unsigned)i - lseg[b]);
            if (pos < (b + 1u) * cap)
                pairs[pos] = sorted[i];
        }
        __syncthreads();
        for (int i = tid; i < nb; i += 256) wcur[i] += lhist[i];
        __syncthreads();
    }
}

// ---------------------------------------------------------------------------
// Dual per-bucket counting sort over 512-node buckets: block b<nb = layer1
// bucket b, else layer2 bucket b-nb. Wave-parallel 512-entry scan.
__global__ __launch_bounds__(256) void csr2_kernel(
    const unsigned* __restrict__ pairs1, const unsigned* __restrict__ pairs2,
    const unsigned* __restrict__ cnt1, const unsigned* __restrict__ cnt2,
    unsigned* __restrict__ rps1, unsigned* __restrict__ rpe1,
    unsigned* __restrict__ rps2, unsigned* __restrict__ rpe2,
    int* __restrict__ esrc1, int* __restrict__ esrc2,
    unsigned cap, int n, int nb) {
    __shared__ unsigned hist[BNODES], excl[BNODES], offs[BNODES];
    __shared__ unsigned wsum[4], woff[4];
    const int side = blockIdx.x / nb;
    const int b = blockIdx.x % nb;
    const unsigned* pairs = side ? pairs2 : pairs1;
    const unsigned* cnt = side ? cnt2 : cnt1;
    unsigned* rps = side ? rps2 : rps1;
    unsigned* rpe = side ? rpe2 : rpe1;
    int* esrc = side ? esrc2 : esrc1;
    const int tid = threadIdx.x;
    const int lane = tid & 63;
    const unsigned base = (unsigned)b * cap;
    unsigned count = cnt[b] - base;
    if (count > cap) count = cap;

    hist[tid] = 0u; hist[tid + 256] = 0u;
    __syncthreads();
    for (unsigned e = tid; e < count; e += 256)
        atomicAdd(&hist[pairs[base + e] >> 17], 1u);
    __syncthreads();
    // wave-parallel exclusive scan of hist[0..512): thread t owns entries 2t,2t+1
    {
        unsigned s0 = hist[2 * tid], s1 = hist[2 * tid + 1];
        unsigned tsum = s0 + s1;
        unsigned incl = tsum;
        #pragma unroll
        for (int off = 1; off < 64; off <<= 1) {
            unsigned t = __shfl_up(incl, off, 64);
            if (lane >= off) incl += t;
        }
        if (lane == 63) wsum[tid >> 6] = incl;
        __syncthreads();
        if (tid == 0) {
            unsigned s = 0;
            #pragma unroll
            for (int w = 0; w < 4; ++w) { unsigned t = wsum[w]; woff[w] = s; s += t; }
        }
        __syncthreads();
        unsigned pre = woff[tid >> 6] + incl - tsum;
        excl[2 * tid] = pre;
        excl[2 * tid + 1] = pre + s0;
    }
    __syncthreads();
    #pragma unroll
    for (int h = 0; h < 2; ++h) {
        int lt = tid + h * 256;
        int node = b * BNODES + lt;
        if (node < n) {
            rps[node] = base + excl[lt];
            rpe[node] = base + excl[lt] + hist[lt];
        }
        offs[lt] = excl[lt];
    }
    __syncthreads();
    for (unsigned e = tid; e < count; e += 256) {
        unsigned p = pairs[base + e];
        unsigned lpos = atomicAdd(&offs[p >> 17], 1u);
        esrc[base + lpos] = (int)(p & 0x1FFFFu);
    }
}

// ---------------------------------------------------------------------------
#define ACC8(v)                                                              \
    a0 += bf_lo((v).x); a1 += bf_hi((v).x);                                  \
    a2 += bf_lo((v).y); a3 += bf_hi((v).y);                                  \
    a4 += bf_lo((v).z); a5 += bf_hi((v).z);                                  \
    a6 += bf_lo((v).w); a7 += bf_hi((v).w);

// Mean-gather, 128-wide bf16 rows. Row = 16 lanes x 16B; 4 edges per load
// instruction; 16-edge main step keeps 4KB/wave in flight.
__global__ __launch_bounds__(256) void gather_mean128_kernel(
    const uint4* __restrict__ featq, const unsigned* __restrict__ rps,
    const unsigned* __restrict__ rpe, const int* __restrict__ esrc,
    uint4* __restrict__ aggq, int n) {
    const int wave = threadIdx.x >> 6;
    const int lane = threadIdx.x & 63;
    const int qi = lane >> 4;     // edge slot 0..3
    const int li = lane & 15;     // 16B block within row
    for (int node = blockIdx.x * 4 + wave; node < n; node += gridDim.x * 4) {
        unsigned rs = rps[node];
        unsigned re = rpe[node];
        float a0 = 0.f, a1 = 0.f, a2 = 0.f, a3 = 0.f;
        float a4 = 0.f, a5 = 0.f, a6 = 0.f, a7 = 0.f;
        unsigned j = rs;
        for (; j + 16 <= re; j += 16) {
            unsigned i0 = (unsigned)esrc[j + qi] * 16u + (unsigned)li;
            unsigned i1 = (unsigned)esrc[j + 4 + qi] * 16u + (unsigned)li;
            unsigned i2 = (unsigned)esrc[j + 8 + qi] * 16u + (unsigned)li;
            unsigned i3 = (unsigned)esrc[j + 12 + qi] * 16u + (unsigned)li;
            uint4 v0 = featq[i0];
            uint4 v1 = featq[i1];
            uint4 v2 = featq[i2];
            uint4 v3 = featq[i3];
            ACC8(v0); ACC8(v1); ACC8(v2); ACC8(v3);
        }
        for (; j + 8 <= re; j += 8) {
            unsigned i0 = (unsigned)esrc[j + qi] * 16u + (unsigned)li;
            unsigned i1 = (unsigned)esrc[j + 4 + qi] * 16u + (unsigned)li;
            uint4 v0 = featq[i0];
            uint4 v1 = featq[i1];
            ACC8(v0); ACC8(v1);
        }
        for (; j + 4 <= re; j += 4) {
            unsigned i0 = (unsigned)esrc[j + qi] * 16u + (unsigned)li;
            uint4 v0 = featq[i0];
            ACC8(v0);
        }
        unsigned rem = re - j;
        if ((unsigned)qi < rem) {
            unsigned i0 = (unsigned)esrc[j + qi] * 16u + (unsigned)li;
            uint4 v0 = featq[i0];
            ACC8(v0);
        }
        a0 += __shfl_xor(a0, 16, 64); a1 += __shfl_xor(a1, 16, 64);
        a2 += __shfl_xor(a2, 16, 64); a3 += __shfl_xor(a3, 16, 64);
        a4 += __shfl_xor(a4, 16, 64); a5 += __shfl_xor(a5, 16, 64);
        a6 += __shfl_xor(a6, 16, 64); a7 += __shfl_xor(a7, 16, 64);
        a0 += __shfl_xor(a0, 32, 64); a1 += __shfl_xor(a1, 32, 64);
        a2 += __shfl_xor(a2, 32, 64); a3 += __shfl_xor(a3, 32, 64);
        a4 += __shfl_xor(a4, 32, 64); a5 += __shfl_xor(a5, 32, 64);
        a6 += __shfl_xor(a6, 32, 64); a7 += __shfl_xor(a7, 32, 64);
        if (lane < 16) {
            float inv = (re > rs) ? 1.0f / (float)(re - rs) : 0.0f;
            uint4 o;
            o.x = f2bf_rne(a0 * inv) | (f2bf_rne(a1 * inv) << 16);
            o.y = f2bf_rne(a2 * inv) | (f2bf_rne(a3 * inv) << 16);
            o.z = f2bf_rne(a4 * inv) | (f2bf_rne(a5 * inv) << 16);
            o.w = f2bf_rne(a6 * inv) | (f2bf_rne(a7 * inv) << 16);
            aggq[(size_t)node * 16 + lane] = o;
        }
    }
}

// ---------------------------------------------------------------------------
// Mean-gather, 64-wide bf16 rows (y2). Row = 8 lanes x 16B; 8 edges per load.
__global__ __launch_bounds__(256) void gather_mean64_kernel(
    const uint4* __restrict__ y2q, const unsigned* __restrict__ rps,
    const unsigned* __restrict__ rpe, const int* __restrict__ esrc,
    uint4* __restrict__ aggyq, int n) {
    const int wave = threadIdx.x >> 6;
    const int lane = threadIdx.x & 63;
    const int oi = lane >> 3;     // edge slot 0..7
    const int li = lane & 7;      // 16B block within row
    for (int node = blockIdx.x * 4 + wave; node < n; node += gridDim.x * 4) {
        unsigned rs = rps[node];
        unsigned re = rpe[node];
        float a0 = 0.f, a1 = 0.f, a2 = 0.f, a3 = 0.f;
        float a4 = 0.f, a5 = 0.f, a6 = 0.f, a7 = 0.f;
        unsigned j = rs;
        for (; j + 16 <= re; j += 16) {
            unsigned i0 = (unsigned)esrc[j + oi] * 8u + (unsigned)li;
            unsigned i1 = (unsigned)esrc[j + 8 + oi] * 8u + (unsigned)li;
            uint4 v0 = y2q[i0];
            uint4 v1 = y2q[i1];
            ACC8(v0); ACC8(v1);
        }
        for (; j + 8 <= re; j += 8) {
            unsigned i0 = (unsigned)esrc[j + oi] * 8u + (unsigned)li;
            uint4 v0 = y2q[i0];
            ACC8(v0);
        }
        unsigned rem = re - j;
        if ((unsigned)oi < rem) {
            unsigned i0 = (unsigned)esrc[j + oi] * 8u + (unsigned)li;
            uint4 v0 = y2q[i0];
            ACC8(v0);
        }
        a0 += __shfl_xor(a0, 8, 64);  a1 += __shfl_xor(a1, 8, 64);
        a2 += __shfl_xor(a2, 8, 64);  a3 += __shfl_xor(a3, 8, 64);
        a4 += __shfl_xor(a4, 8, 64);  a5 += __shfl_xor(a5, 8, 64);
        a6 += __shfl_xor(a6, 8, 64);  a7 += __shfl_xor(a7, 8, 64);
        a0 += __shfl_xor(a0, 16, 64); a1 += __shfl_xor(a1, 16, 64);
        a2 += __shfl_xor(a2, 16, 64); a3 += __shfl_xor(a3, 16, 64);
        a4 += __shfl_xor(a4, 16, 64); a5 += __shfl_xor(a5, 16, 64);
        a6 += __shfl_xor(a6, 16, 64); a7 += __shfl_xor(a7, 16, 64);
        a0 += __shfl_xor(a0, 32, 64); a1 += __shfl_xor(a1, 32, 64);
        a2 += __shfl_xor(a2, 32, 64); a3 += __shfl_xor(a3, 32, 64);
        a4 += __shfl_xor(a4, 32, 64); a5 += __shfl_xor(a5, 32, 64);
        a6 += __shfl_xor(a6, 32, 64); a7 += __shfl_xor(a7, 32, 64);
        if (lane < 8) {
            float inv = (re > rs) ? 1.0f / (float)(re - rs) : 0.0f;
            uint4 o;
            o.x = f2bf_rne(a0 * inv) | (f2bf_rne(a1 * inv) << 16);
            o.y = f2bf_rne(a2 * inv) | (f2bf_rne(a3 * inv) << 16);
            o.z = f2bf_rne(a4 * inv) | (f2bf_rne(a5 * inv) << 16);
            o.w = f2bf_rne(a6 * inv) | (f2bf_rne(a7 * inv) << 16);
            aggyq[(size_t)node * 8 + lane] = o;
        }
    }
}

// ---------------------------------------------------------------------------
// GEMM1 (MFMA): hb = relu([agg|xb] @ [W1l;W1r] + b1), N=128, K=256, bf16 out.
__global__ __launch_bounds__(256, 2) void gemm1_kernel(
    const unsigned short* __restrict__ agg, const unsigned short* __restrict__ xb,
    const float* __restrict__ Wl, const float* __restrict__ Wr,
    const float* __restrict__ b, unsigned short* __restrict__ hb, int n) {
    __shared__ __align__(16) unsigned short sB[256 * FEAT];   // 64 KB
    const int tid = threadIdx.x;

    for (int idx = tid; idx < 256 * FEAT; idx += 256) {
        int k = idx >> 7, col = idx & 127;
        float w = (k < 128) ? Wl[k * FEAT + col] : Wr[(k - 128) * FEAT + col];
        int pos = ((col >> 4) * 8 + (k >> 5)) * 512
                + ((((k >> 3) & 3) * 16 + (col & 15)) * 8) + (k & 7);
        sB[pos] = (unsigned short)f2bf_rne(w);
    }
    __syncthreads();

    const int wv = tid >> 6, lane = tid & 63;
    const int cg = wv & 1;
    const int ms = wv >> 1;
    const int g = lane >> 4, c15 = lane & 15;

    bf16x8 bf[4][8];
    #pragma unroll
    for (int ct = 0; ct < 4; ++ct)
        #pragma unroll
        for (int ks = 0; ks < 8; ++ks)
            bf[ct][ks] = *(const bf16x8*)&sB[(((cg * 4 + ct) * 8 + ks) * 64 + lane) * 8];

    float bias[4];
    #pragma unroll
    for (int ct = 0; ct < 4; ++ct) bias[ct] = b[cg * 64 + ct * 16 + c15];

    const int ntiles = (n + 31) >> 5;
    for (int tile = blockIdx.x; tile < ntiles; tile += gridDim.x) {
        const int base = tile * 32;
        const int row = base + ms * 16 + c15;
        bf16x8 af[8];
        #pragma unroll
        for (int ks = 0; ks < 8; ++ks) {
            bf16x8 a = {0, 0, 0, 0, 0, 0, 0, 0};
            if (row < n) {
                int karr = ks * 32 + g * 8;
                const unsigned short* p = (ks < 4)
                    ? &agg[(size_t)row * FEAT + karr]
                    : &xb[(size_t)row * FEAT + (karr - 128)];
                a = *(const bf16x8*)p;
            }
            af[ks] = a;
        }
        f32x4 z = {0.f, 0.f, 0.f, 0.f};
        f32x4 acc[4] = {z, z, z, z};
        #pragma unroll
        for (int ks = 0; ks < 8; ++ks)
            #pragma unroll
            for (int ct = 0; ct < 4; ++ct)
                acc[ct] = __builtin_amdgcn_mfma_f32_16x16x32_bf16(
                    af[ks], bf[ct][ks], acc[ct], 0, 0, 0);
        #pragma unroll
        for (int ct = 0; ct < 4; ++ct) {
            const int col = cg * 64 + ct * 16 + c15;
            #pragma unroll
            for (int r = 0; r < 4; ++r) {
                int node = base + ms * 16 + g * 4 + r;
                if (node < n) {
                    float v = fmaxf(acc[ct][r] + bias[ct], 0.f);
                    hb[(size_t)node * FEAT + col] = (unsigned short)f2bf_rne(v);
                }
            }
        }
    }
}

// ---------------------------------------------------------------------------
// y2 = hb @ W2l (MFMA), N=64, K=128, bf16 out (no bias).
__global__ __launch_bounds__(256, 2) void gemmy2_kernel(
    const unsigned short* __restrict__ hb, const float* __restrict__ Wl,
    unsigned short* __restrict__ y2, int n) {
    __shared__ __align__(16) unsigned short sB[128 * OUTF];   // 16 KB
    const int tid = threadIdx.x;

    for (int idx = tid; idx < 128 * OUTF; idx += 256) {
        int k = idx >> 6, col = idx & 63;
        float w = Wl[k * OUTF + col];
        int pos = ((col >> 4) * 4 + (k >> 5)) * 512
                + ((((k >> 3) & 3) * 16 + (col & 15)) * 8) + (k & 7);
        sB[pos] = (unsigned short)f2bf_rne(w);
    }
    __syncthreads();

    const int wv = tid >> 6, lane = tid & 63;
    const int g = lane >> 4, c15 = lane & 15;

    bf16x8 bf[4][4];
    #pragma unroll
    for (int ct = 0; ct < 4; ++ct)
        #pragma unroll
        for (int ks = 0; ks < 4; ++ks)
            bf[ct][ks] = *(const bf16x8*)&sB[((ct * 4 + ks) * 64 + lane) * 8];

    const int ntiles = (n + 63) >> 6;
    for (int tile = blockIdx.x; tile < ntiles; tile += gridDim.x) {
        const int base = tile * 64;
        const int row = base + wv * 16 + c15;
        bf16x8 af[4];
        #pragma unroll
        for (int ks = 0; ks < 4; ++ks) {
            bf16x8 a = {0, 0, 0, 0, 0, 0, 0, 0};
            if (row < n) a = *(const bf16x8*)&hb[(size_t)row * FEAT + ks * 32 + g * 8];
            af[ks] = a;
        }
        f32x4 z = {0.f, 0.f, 0.f, 0.f};
        f32x4 acc[4] = {z, z, z, z};
        #pragma unroll
        for (int ks = 0; ks < 4; ++ks)
            #pragma unroll
            for (int ct = 0; ct < 4; ++ct)
                acc[ct] = __builtin_amdgcn_mfma_f32_16x16x32_bf16(
                    af[ks], bf[ct][ks], acc[ct], 0, 0, 0);
        #pragma unroll
        for (int ct = 0; ct < 4; ++ct) {
            const int col = ct * 16 + c15;
            #pragma unroll
            for (int r = 0; r < 4; ++r) {
                int node = base + wv * 16 + g * 4 + r;
                if (node < n)
                    y2[(size_t)node * OUTF + col] = (unsigned short)f2bf_rne(acc[ct][r]);
            }
        }
    }
}

// ---------------------------------------------------------------------------
// GEMM2b (MFMA) + softmax: out = softmax(hb@W2r + meanY2 + b2), N=64, K=128.
__global__ __launch_bounds__(256, 2) void gemm2b_kernel(
    const unsigned short* __restrict__ hb, const unsigned short* __restrict__ aggy,
    const float* __restrict__ Wr, const float* __restrict__ b,
    float* __restrict__ out, int n) {
    __shared__ __align__(16) unsigned short sB[128 * OUTF];   // 16 KB
    const int tid = threadIdx.x;

    for (int idx = tid; idx < 128 * OUTF; idx += 256) {
        int k = idx >> 6, col = idx & 63;
        float w = Wr[k * OUTF + col];
        int pos = ((col >> 4) * 4 + (k >> 5)) * 512
                + ((((k >> 3) & 3) * 16 + (col & 15)) * 8) + (k & 7);
        sB[pos] = (unsigned short)f2bf_rne(w);
    }
    __syncthreads();

    const int wv = tid >> 6, lane = tid & 63;
    const int g = lane >> 4, c15 = lane & 15;

    bf16x8 bf[4][4];
    #pragma unroll
    for (int ct = 0; ct < 4; ++ct)
        #pragma unroll
        for (int ks = 0; ks < 4; ++ks)
            bf[ct][ks] = *(const bf16x8*)&sB[((ct * 4 + ks) * 64 + lane) * 8];

    float bias[4];
    #pragma unroll
    for (int ct = 0; ct < 4; ++ct) bias[ct] = b[ct * 16 + c15];

    const int ntiles = (n + 63) >> 6;
    for (int tile = blockIdx.x; tile < ntiles; tile += gridDim.x) {
        const int base = tile * 64;
        const int row = base + wv * 16 + c15;
        bf16x8 af[4];
        #pragma unroll
        for (int ks = 0; ks < 4; ++ks) {
            bf16x8 a = {0, 0, 0, 0, 0, 0, 0, 0};
            if (row < n) a = *(const bf16x8*)&hb[(size_t)row * FEAT + ks * 32 + g * 8];
            af[ks] = a;
        }
        f32x4 z = {0.f, 0.f, 0.f, 0.f};
        f32x4 acc[4] = {z, z, z, z};
        #pragma unroll
        for (int ks = 0; ks < 4; ++ks)
            #pragma unroll
            for (int ct = 0; ct < 4; ++ct)
                acc[ct] = __builtin_amdgcn_mfma_f32_16x16x32_bf16(
                    af[ks], bf[ct][ks], acc[ct], 0, 0, 0);

        #pragma unroll
        for (int r = 0; r < 4; ++r) {
            int node = base + wv * 16 + g * 4 + r;
            bool ok = node < n;
            float v[4];
            #pragma unroll
            for (int ct = 0; ct < 4; ++ct) {
                float my = 0.f;
                if (ok) {
                    unsigned short u = aggy[(size_t)node * OUTF + ct * 16 + c15];
                    my = __uint_as_float((unsigned)u << 16);
                }
                v[ct] = acc[ct][r] + bias[ct] + my;
            }
            float m = fmaxf(fmaxf(v[0], v[1]), fmaxf(v[2], v[3]));
            #pragma unroll
            for (int off = 8; off > 0; off >>= 1)
                m = fmaxf(m, __shfl_xor(m, off, 64));
            float e0 = __expf(v[0] - m), e1 = __expf(v[1] - m);
            float e2 = __expf(v[2] - m), e3 = __expf(v[3] - m);
            float s = e0 + e1 + e2 + e3;
            #pragma unroll
            for (int off = 8; off > 0; off >>= 1)
                s += __shfl_xor(s, off, 64);
            float inv = 1.0f / s;
            if (ok) {
                out[(size_t)node * OUTF + c15]      = e0 * inv;
                out[(size_t)node * OUTF + 16 + c15] = e1 * inv;
                out[(size_t)node * OUTF + 32 + c15] = e2 * inv;
                out[(size_t)node * OUTF + 48 + c15] = e3 * inv;
            }
        }
    }
}

// ---------------------------------------------------------------------------
extern "C" void kernel_launch(void* const* d_in, const int* in_sizes, int n_in,
                              void* d_out, int out_size, void* d_ws, size_t ws_size,
                              hipStream_t stream) {
    const float* x   = (const float*)d_in[0];
    const float* W1l = (const float*)d_in[1];
    const float* W1r = (const float*)d_in[2];
    const float* b1  = (const float*)d_in[3];
    const float* W2l = (const float*)d_in[4];
    const float* W2r = (const float*)d_in[5];
    const float* b2  = (const float*)d_in[6];
    const void*  ei1 = d_in[7];
    const void*  ei2 = d_in[8];
    float* out = (float*)d_out;

    const int n  = in_sizes[0] / FEAT;   // 100000
    const int e1 = in_sizes[7] / 2;      // 1600000
    const int e2 = in_sizes[8] / 2;
    const int emax = (e1 > e2) ? e1 : e2;

    const int nb = (n + BNODES - 1) >> BSH;                // 196 buckets
    if (nb > NBMAX) return;
    unsigned cap = (unsigned)(emax / nb + emax / (4 * nb) + 512);
    cap = (cap + 63u) & ~63u;                              // ~10752

    // Workspace: [flag 256B][xb 25.6M][hb 25.6M][aggregion 25.6M (pairs1|pairs2
    // alias pre-gather; then agg/y2/aggy)][cnt1 cnt2][rps1 rpe1 rps2 rpe2]
    // [esrc1][esrc2][pad]  ~= 96 MB
    char* ws = (char*)d_ws;
    const size_t fBytes   = (size_t)n * FEAT * 2;          // 25.6 MB
    const size_t cntBytes = ((size_t)NBMAX * 4 + 255) & ~(size_t)255;
    const size_t rpBytes  = (((size_t)n * 4) + 255) & ~(size_t)255;
    const size_t bktBytes = (((size_t)nb * cap * 4) + 255) & ~(size_t)255;  // ~8.4 MB
    if (2 * bktBytes > fBytes) return;   // pairs must fit in agg region
    unsigned*       flag = (unsigned*)ws;
    unsigned short* xb   = (unsigned short*)(ws + 256);
    unsigned short* hb   = (unsigned short*)(ws + 256 + fBytes);
    char*           aggr = ws + 256 + 2 * fBytes;
    unsigned short* agg  = (unsigned short*)aggr;
    unsigned short* y2   = agg;                         // reused after gemm1
    unsigned short* aggy = agg + (size_t)n * OUTF;      // second half of agg region
    unsigned* pairs1 = (unsigned*)aggr;                 // alias: dead before gather128
    unsigned* pairs2 = (unsigned*)(aggr + bktBytes);
    char* p = ws + 256 + 3 * fBytes;
    unsigned* cnt1 = (unsigned*)p;            p += cntBytes;
    unsigned* cnt2 = (unsigned*)p;            p += cntBytes;
    unsigned* rps1 = (unsigned*)p;            p += rpBytes;
    unsigned* rpe1 = (unsigned*)p;            p += rpBytes;
    unsigned* rps2 = (unsigned*)p;            p += rpBytes;
    unsigned* rpe2 = (unsigned*)p;            p += rpBytes;
    int*      esrc1 = (int*)p;                p += bktBytes;
    int*      esrc2 = (int*)p;                p += bktBytes;
    p += 256;
    if ((size_t)(p - ws) > ws_size) return;

    hipMemsetAsync(flag, 0, 4, stream);
    detect_idx_kernel<<<1, 256, 0, stream>>>((const unsigned*)ei1, flag);
    convert_kernel<<<2048, 256, 0, stream>>>(x, xb, in_sizes[0] / 4);

    const int gatherGrid = (n + 3) / 4;       // one node per wave, 4 waves/block

    // ---- dual CSR build (both layers, 2 dispatches) ----
    init_cnt2_kernel<<<(nb + 255) / 256, 256, 0, stream>>>(cnt1, cnt2, cap, nb);
    bucket2_kernel<<<2 * BUCKET_BLOCKS, 256, 0, stream>>>(
        ei1, ei2, pairs1, pairs2, cnt1, cnt2, flag, e1, e2, cap, nb);
    csr2_kernel<<<2 * nb, 256, 0, stream>>>(
        pairs1, pairs2, cnt1, cnt2, rps1, rpe1, rps2, rpe2, esrc1, esrc2, cap, n, nb);

    // ---- layer 1 ----
    gather_mean128_kernel<<<gatherGrid, 256, 0, stream>>>((const uint4*)xb, rps1, rpe1,
                                                          esrc1, (uint4*)agg, n);
    gemm1_kernel<<<640, 256, 0, stream>>>(agg, xb, W1l, W1r, b1, hb, n);

    // ---- layer 2 ----
    gemmy2_kernel<<<512, 256, 0, stream>>>(hb, W2l, y2, n);
    gather_mean64_kernel<<<gatherGrid, 256, 0, stream>>>((const uint4*)y2, rps2, rpe2,
                                                         esrc2, (uint4*)aggy, n);
    gemm2b_kernel<<<512, 256, 0, stream>>>(hb, aggy, W2r, b2, out, n);
}

// Round 16
// 257.031 us; speedup vs baseline: 1.0006x; 1.0006x over previous
//
#include <hip/hip_runtime.h>

// GraphSAGE 2-layer, bf16 feature plane + MFMA GEMMs + fused dual-CSR build.
// SINGLE-VARIABLE EXPERIMENT on top of the validated R15 baseline (257 us):
//   ONLY change = gathers use v_dot2_f32_bf16 inline asm for the bf16
//   accumulate (halves unpack VALU). Setup path (memset+detect+init_cnt2)
//   kept exactly as validated, to isolate R13's replay-divergence culprit.
// N=100000, E=1600000, IN=HID=128, OUT=64; edge_index int32 or int64.

#define FEAT 128
#define OUTF 64
#define BSH 9                   // 512 nodes per bucket
#define BNODES 512
#define NBMAX 256               // max buckets
#define BUCKET_BLOCKS 512       // blocks per edge-set in bucket2
#define STAGE 2048              // edges sorted+flushed per stage (8/thread)

typedef __attribute__((ext_vector_type(8))) short bf16x8;
typedef __attribute__((ext_vector_type(4))) float f32x4;

__device__ __forceinline__ unsigned f2bf_rne(float f) {
    unsigned u = __float_as_uint(f);
    return (u + 0x7fffu + ((u >> 16) & 1u)) >> 16;
}
__device__ __forceinline__ float bf_lo(unsigned u) { return __uint_as_float(u << 16); }
__device__ __forceinline__ float bf_hi(unsigned u) { return __uint_as_float(u & 0xffff0000u); }

// acc += selected bf16 half of u (sel = packed v2bf16 (1,0) or (0,1)).
__device__ __forceinline__ void d2acc(float& a, unsigned u, unsigned sel) {
    asm("v_dot2_f32_bf16 %0, %1, %2, %0" : "+v"(a) : "v"(u), "v"(sel));
}
#define ACC8(v)                                                              \
    d2acc(a0, (v).x, selLo); d2acc(a1, (v).x, selHi);                        \
    d2acc(a2, (v).y, selLo); d2acc(a3, (v).y, selHi);                        \
    d2acc(a4, (v).z, selLo); d2acc(a5, (v).z, selHi);                        \
    d2acc(a6, (v).w, selLo); d2acc(a7, (v).w, selHi);

// ---------------------------------------------------------------------------
// int64 vs int32 detection: indices < 100000 so int64 => odd 32-bit words all 0.
__global__ void detect_idx_kernel(const unsigned* __restrict__ ei, unsigned* __restrict__ flag) {
    unsigned v = ei[2 * threadIdx.x + 1];
    if (v != 0u) atomicOr(flag, 1u);
}

// ---------------------------------------------------------------------------
__global__ __launch_bounds__(256) void convert_kernel(
    const float* __restrict__ in, unsigned short* __restrict__ outb, int total4) {
    for (int i = blockIdx.x * 256 + threadIdx.x; i < total4; i += gridDim.x * 256) {
        float4 v = *(const float4*)&in[(size_t)i * 4];
        ushort4 o;
        o.x = (unsigned short)f2bf_rne(v.x);
        o.y = (unsigned short)f2bf_rne(v.y);
        o.z = (unsigned short)f2bf_rne(v.z);
        o.w = (unsigned short)f2bf_rne(v.w);
        *(ushort4*)&outb[(size_t)i * 4] = o;
    }
}

// ---------------------------------------------------------------------------
__global__ __launch_bounds__(256) void init_cnt2_kernel(
    unsigned* __restrict__ cnt1, unsigned* __restrict__ cnt2, unsigned cap, int nb) {
    int i = blockIdx.x * 256 + threadIdx.x;
    if (i < nb) { cnt1[i] = (unsigned)i * cap; cnt2[i] = (unsigned)i * cap; }
}

// ---------------------------------------------------------------------------
// Dual bucket scatter with LDS stage-sort + coalesced flush.
__global__ __launch_bounds__(256) void bucket2_kernel(
    const void* __restrict__ ei1_raw, const void* __restrict__ ei2_raw,
    unsigned* __restrict__ pairs1, unsigned* __restrict__ pairs2,
    unsigned* __restrict__ cnt1, unsigned* __restrict__ cnt2,
    const unsigned* __restrict__ flag, int e1, int e2, unsigned cap, int nb) {
    __shared__ unsigned hist[NBMAX];    // whole-chunk totals
    __shared__ unsigned wcur[NBMAX];    // global write cursor per bucket
    __shared__ unsigned lhist[NBMAX];   // per-stage hist
    __shared__ unsigned lseg[NBMAX];    // per-stage exclusive scan
    __shared__ unsigned loffs[NBMAX];   // per-stage scatter cursor
    __shared__ unsigned sorted[STAGE];
    __shared__ unsigned char sbid[STAGE];
    __shared__ unsigned wsum[2];
    const int tid = threadIdx.x;
    const int lane = tid & 63;
    const bool is32 = (*flag != 0u);
    const int side = blockIdx.x / BUCKET_BLOCKS;
    const int bid = blockIdx.x % BUCKET_BLOCKS;
    const void* ei_raw = side ? ei2_raw : ei1_raw;
    unsigned* pairs = side ? pairs2 : pairs1;
    unsigned* cnt = side ? cnt2 : cnt1;
    const int nedge = side ? e2 : e1;
    const int chunk = (nedge + BUCKET_BLOCKS - 1) / BUCKET_BLOCKS;
    const int e0 = bid * chunk;
    const int eEnd = min(e0 + chunk, nedge);
    if (e0 >= nedge) return;

    // phase 1: whole-chunk histogram
    for (int i = tid; i < nb; i += 256) hist[i] = 0u;
    __syncthreads();
    for (int e = e0 + tid; e < eEnd; e += 256) {
        int dst = is32 ? ((const int*)ei_raw)[nedge + e]
                       : (int)((const long long*)ei_raw)[nedge + e];
        atomicAdd(&hist[(unsigned)dst >> BSH], 1u);
    }
    __syncthreads();
    // phase 2: one reservation per bucket
    for (int i = tid; i < nb; i += 256) {
        unsigned c = hist[i];
        wcur[i] = c ? atomicAdd(&cnt[i], c) : 0u;
    }
    __syncthreads();

    // phase 3: staged sort + coalesced flush
    for (int s0 = e0; s0 < eEnd; s0 += STAGE) {
        const int sEnd = min(s0 + STAGE, eEnd);
        const int cs = sEnd - s0;
        for (int i = tid; i < NBMAX; i += 256) lhist[i] = 0u;
        __syncthreads();
        unsigned myp[8];
        unsigned myb[8];
        bool myv[8];
        #pragma unroll
        for (int k = 0; k < 8; ++k) {
            int e = s0 + k * 256 + tid;
            bool valid = e < sEnd;
            myv[k] = valid;
            int src = 0, dst = 0;
            if (valid) {
                if (is32) {
                    const int* ei = (const int*)ei_raw;
                    src = ei[e]; dst = ei[nedge + e];
                } else {
                    const long long* ei = (const long long*)ei_raw;
                    src = (int)ei[e]; dst = (int)ei[nedge + e];
                }
            }
            unsigned b = (unsigned)dst >> BSH;
            myp[k] = (((unsigned)dst & (BNODES - 1u)) << 17) | (unsigned)src;
            myb[k] = b;
            if (valid) atomicAdd(&lhist[b], 1u);
        }
        __syncthreads();
        // wave-parallel exclusive scan over 256 slots: threads 0..127, 2 each
        unsigned incl = 0, tsum = 0, sv0 = 0;
        if (tid < 128) {
            sv0 = lhist[2 * tid];
            unsigned sv1 = lhist[2 * tid + 1];
            tsum = sv0 + sv1;
            incl = tsum;
            #pragma unroll
            for (int off = 1; off < 64; off <<= 1) {
                unsigned t = __shfl_up(incl, off, 64);
                if (lane >= off) incl += t;
            }
            if (lane == 63) wsum[tid >> 6] = incl;
        }
        __syncthreads();
        if (tid < 128) {
            unsigned pre = (tid >> 6 ? wsum[0] : 0u) + incl - tsum;
            lseg[2 * tid] = pre;
            lseg[2 * tid + 1] = pre + sv0;
            loffs[2 * tid] = pre;
            loffs[2 * tid + 1] = pre + sv0;
        }
        __syncthreads();
        #pragma unroll
        for (int k = 0; k < 8; ++k) {
            if (myv[k]) {
                unsigned p = atomicAdd(&loffs[myb[k]], 1u);
                sorted[p] = myp[k];
                sbid[p] = (unsigned char)myb[k];
            }
        }
        __syncthreads();
        for (int i = tid; i < cs; i += 256) {
            unsigned b = sbid[i];
            unsigned pos = wcur[b] + ((unsigned)i - lseg[b]);
            if (pos < (b + 1u) * cap)
                pairs[pos] = sorted[i];
        }
        __syncthreads();
        for (int i = tid; i < nb; i += 256) wcur[i] += lhist[i];
        __syncthreads();
    }
}

// ---------------------------------------------------------------------------
// Dual per-bucket counting sort over 512-node buckets.
__global__ __launch_bounds__(256) void csr2_kernel(
    const unsigned* __restrict__ pairs1, const unsigned* __restrict__ pairs2,
    const unsigned* __restrict__ cnt1, const unsigned* __restrict__ cnt2,
    unsigned* __restrict__ rps1, unsigned* __restrict__ rpe1,
    unsigned* __restrict__ rps2, unsigned* __restrict__ rpe2,
    int* __restrict__ esrc1, int* __restrict__ esrc2,
    unsigned cap, int n, int nb) {
    __shared__ unsigned hist[BNODES], excl[BNODES], offs[BNODES];
    __shared__ unsigned wsum[4], woff[4];
    const int side = blockIdx.x / nb;
    const int b = blockIdx.x % nb;
    const unsigned* pairs = side ? pairs2 : pairs1;
    const unsigned* cnt = side ? cnt2 : cnt1;
    unsigned* rps = side ? rps2 : rps1;
    unsigned* rpe = side ? rpe2 : rpe1;
    int* esrc = side ? esrc2 : esrc1;
    const int tid = threadIdx.x;
    const int lane = tid & 63;
    const unsigned base = (unsigned)b * cap;
    unsigned count = cnt[b] - base;
    if (count > cap) count = cap;

    hist[tid] = 0u; hist[tid + 256] = 0u;
    __syncthreads();
    for (unsigned e = tid; e < count; e += 256)
        atomicAdd(&hist[pairs[base + e] >> 17], 1u);
    __syncthreads();
    // wave-parallel exclusive scan of hist[0..512): thread t owns entries 2t,2t+1
    {
        unsigned s0 = hist[2 * tid], s1 = hist[2 * tid + 1];
        unsigned tsum = s0 + s1;
        unsigned incl = tsum;
        #pragma unroll
        for (int off = 1; off < 64; off <<= 1) {
            unsigned t = __shfl_up(incl, off, 64);
            if (lane >= off) incl += t;
        }
        if (lane == 63) wsum[tid >> 6] = incl;
        __syncthreads();
        if (tid == 0) {
            unsigned s = 0;
            #pragma unroll
            for (int w = 0; w < 4; ++w) { unsigned t = wsum[w]; woff[w] = s; s += t; }
        }
        __syncthreads();
        unsigned pre = woff[tid >> 6] + incl - tsum;
        excl[2 * tid] = pre;
        excl[2 * tid + 1] = pre + s0;
    }
    __syncthreads();
    #pragma unroll
    for (int h = 0; h < 2; ++h) {
        int lt = tid + h * 256;
        int node = b * BNODES + lt;
        if (node < n) {
            rps[node] = base + excl[lt];
            rpe[node] = base + excl[lt] + hist[lt];
        }
        offs[lt] = excl[lt];
    }
    __syncthreads();
    for (unsigned e = tid; e < count; e += 256) {
        unsigned p = pairs[base + e];
        unsigned lpos = atomicAdd(&offs[p >> 17], 1u);
        esrc[base + lpos] = (int)(p & 0x1FFFFu);
    }
}

// ---------------------------------------------------------------------------
// Mean-gather, 128-wide bf16 rows. Row = 16 lanes x 16B; 4 edges per load
// instruction; 16-edge main step keeps 4KB/wave in flight. dot2 accumulate.
__global__ __launch_bounds__(256) void gather_mean128_kernel(
    const uint4* __restrict__ featq, const unsigned* __restrict__ rps,
    const unsigned* __restrict__ rpe, const int* __restrict__ esrc,
    uint4* __restrict__ aggq, int n) {
    const int wave = threadIdx.x >> 6;
    const int lane = threadIdx.x & 63;
    const int qi = lane >> 4;     // edge slot 0..3
    const int li = lane & 15;     // 16B block within row
    const unsigned selLo = 0x00003F80u;   // v2bf16 (1,0)
    const unsigned selHi = 0x3F800000u;   // v2bf16 (0,1)
    for (int node = blockIdx.x * 4 + wave; node < n; node += gridDim.x * 4) {
        unsigned rs = rps[node];
        unsigned re = rpe[node];
        float a0 = 0.f, a1 = 0.f, a2 = 0.f, a3 = 0.f;
        float a4 = 0.f, a5 = 0.f, a6 = 0.f, a7 = 0.f;
        unsigned j = rs;
        for (; j + 16 <= re; j += 16) {
            unsigned i0 = (unsigned)esrc[j + qi] * 16u + (unsigned)li;
            unsigned i1 = (unsigned)esrc[j + 4 + qi] * 16u + (unsigned)li;
            unsigned i2 = (unsigned)esrc[j + 8 + qi] * 16u + (unsigned)li;
            unsigned i3 = (unsigned)esrc[j + 12 + qi] * 16u + (unsigned)li;
            uint4 v0 = featq[i0];
            uint4 v1 = featq[i1];
            uint4 v2 = featq[i2];
            uint4 v3 = featq[i3];
            ACC8(v0); ACC8(v1); ACC8(v2); ACC8(v3);
        }
        for (; j + 8 <= re; j += 8) {
            unsigned i0 = (unsigned)esrc[j + qi] * 16u + (unsigned)li;
            unsigned i1 = (unsigned)esrc[j + 4 + qi] * 16u + (unsigned)li;
            uint4 v0 = featq[i0];
            uint4 v1 = featq[i1];
            ACC8(v0); ACC8(v1);
        }
        for (; j + 4 <= re; j += 4) {
            unsigned i0 = (unsigned)esrc[j + qi] * 16u + (unsigned)li;
            uint4 v0 = featq[i0];
            ACC8(v0);
        }
        unsigned rem = re - j;
        if ((unsigned)qi < rem) {
            unsigned i0 = (unsigned)esrc[j + qi] * 16u + (unsigned)li;
            uint4 v0 = featq[i0];
            ACC8(v0);
        }
        a0 += __shfl_xor(a0, 16, 64); a1 += __shfl_xor(a1, 16, 64);
        a2 += __shfl_xor(a2, 16, 64); a3 += __shfl_xor(a3, 16, 64);
        a4 += __shfl_xor(a4, 16, 64); a5 += __shfl_xor(a5, 16, 64);
        a6 += __shfl_xor(a6, 16, 64); a7 += __shfl_xor(a7, 16, 64);
        a0 += __shfl_xor(a0, 32, 64); a1 += __shfl_xor(a1, 32, 64);
        a2 += __shfl_xor(a2, 32, 64); a3 += __shfl_xor(a3, 32, 64);
        a4 += __shfl_xor(a4, 32, 64); a5 += __shfl_xor(a5, 32, 64);
        a6 += __shfl_xor(a6, 32, 64); a7 += __shfl_xor(a7, 32, 64);
        if (lane < 16) {
            float inv = (re > rs) ? 1.0f / (float)(re - rs) : 0.0f;
            uint4 o;
            o.x = f2bf_rne(a0 * inv) | (f2bf_rne(a1 * inv) << 16);
            o.y = f2bf_rne(a2 * inv) | (f2bf_rne(a3 * inv) << 16);
            o.z = f2bf_rne(a4 * inv) | (f2bf_rne(a5 * inv) << 16);
            o.w = f2bf_rne(a6 * inv) | (f2bf_rne(a7 * inv) << 16);
            aggq[(size_t)node * 16 + lane] = o;
        }
    }
}

// ---------------------------------------------------------------------------
// Mean-gather, 64-wide bf16 rows (y2). Row = 8 lanes x 16B; 8 edges per load.
__global__ __launch_bounds__(256) void gather_mean64_kernel(
    const uint4* __restrict__ y2q, const unsigned* __restrict__ rps,
    const unsigned* __restrict__ rpe, const int* __restrict__ esrc,
    uint4* __restrict__ aggyq, int n) {
    const int wave = threadIdx.x >> 6;
    const int lane = threadIdx.x & 63;
    const int oi = lane >> 3;     // edge slot 0..7
    const int li = lane & 7;      // 16B block within row
    const unsigned selLo = 0x00003F80u;
    const unsigned selHi = 0x3F800000u;
    for (int node = blockIdx.x * 4 + wave; node < n; node += gridDim.x * 4) {
        unsigned rs = rps[node];
        unsigned re = rpe[node];
        float a0 = 0.f, a1 = 0.f, a2 = 0.f, a3 = 0.f;
        float a4 = 0.f, a5 = 0.f, a6 = 0.f, a7 = 0.f;
        unsigned j = rs;
        for (; j + 16 <= re; j += 16) {
            unsigned i0 = (unsigned)esrc[j + oi] * 8u + (unsigned)li;
            unsigned i1 = (unsigned)esrc[j + 8 + oi] * 8u + (unsigned)li;
            uint4 v0 = y2q[i0];
            uint4 v1 = y2q[i1];
            ACC8(v0); ACC8(v1);
        }
        for (; j + 8 <= re; j += 8) {
            unsigned i0 = (unsigned)esrc[j + oi] * 8u + (unsigned)li;
            uint4 v0 = y2q[i0];
            ACC8(v0);
        }
        unsigned rem = re - j;
        if ((unsigned)oi < rem) {
            unsigned i0 = (unsigned)esrc[j + oi] * 8u + (unsigned)li;
            uint4 v0 = y2q[i0];
            ACC8(v0);
        }
        a0 += __shfl_xor(a0, 8, 64);  a1 += __shfl_xor(a1, 8, 64);
        a2 += __shfl_xor(a2, 8, 64);  a3 += __shfl_xor(a3, 8, 64);
        a4 += __shfl_xor(a4, 8, 64);  a5 += __shfl_xor(a5, 8, 64);
        a6 += __shfl_xor(a6, 8, 64);  a7 += __shfl_xor(a7, 8, 64);
        a0 += __shfl_xor(a0, 16, 64); a1 += __shfl_xor(a1, 16, 64);
        a2 += __shfl_xor(a2, 16, 64); a3 += __shfl_xor(a3, 16, 64);
        a4 += __shfl_xor(a4, 16, 64); a5 += __shfl_xor(a5, 16, 64);
        a6 += __shfl_xor(a6, 16, 64); a7 += __shfl_xor(a7, 16, 64);
        a0 += __shfl_xor(a0, 32, 64); a1 += __shfl_xor(a1, 32, 64);
        a2 += __shfl_xor(a2, 32, 64); a3 += __shfl_xor(a3, 32, 64);
        a4 += __shfl_xor(a4, 32, 64); a5 += __shfl_xor(a5, 32, 64);
        a6 += __shfl_xor(a6, 32, 64); a7 += __shfl_xor(a7, 32, 64);
        if (lane < 8) {
            float inv = (re > rs) ? 1.0f / (float)(re - rs) : 0.0f;
            uint4 o;
            o.x = f2bf_rne(a0 * inv) | (f2bf_rne(a1 * inv) << 16);
            o.y = f2bf_rne(a2 * inv) | (f2bf_rne(a3 * inv) << 16);
            o.z = f2bf_rne(a4 * inv) | (f2bf_rne(a5 * inv) << 16);
            o.w = f2bf_rne(a6 * inv) | (f2bf_rne(a7 * inv) << 16);
            aggyq[(size_t)node * 8 + lane] = o;
        }
    }
}

// ---------------------------------------------------------------------------
// GEMM1 (MFMA): hb = relu([agg|xb] @ [W1l;W1r] + b1), N=128, K=256, bf16 out.
__global__ __launch_bounds__(256, 2) void gemm1_kernel(
    const unsigned short* __restrict__ agg, const unsigned short* __restrict__ xb,
    const float* __restrict__ Wl, const float* __restrict__ Wr,
    const float* __restrict__ b, unsigned short* __restrict__ hb, int n) {
    __shared__ __align__(16) unsigned short sB[256 * FEAT];   // 64 KB
    const int tid = threadIdx.x;

    for (int idx = tid; idx < 256 * FEAT; idx += 256) {
        int k = idx >> 7, col = idx & 127;
        float w = (k < 128) ? Wl[k * FEAT + col] : Wr[(k - 128) * FEAT + col];
        int pos = ((col >> 4) * 8 + (k >> 5)) * 512
                + ((((k >> 3) & 3) * 16 + (col & 15)) * 8) + (k & 7);
        sB[pos] = (unsigned short)f2bf_rne(w);
    }
    __syncthreads();

    const int wv = tid >> 6, lane = tid & 63;
    const int cg = wv & 1;
    const int ms = wv >> 1;
    const int g = lane >> 4, c15 = lane & 15;

    bf16x8 bf[4][8];
    #pragma unroll
    for (int ct = 0; ct < 4; ++ct)
        #pragma unroll
        for (int ks = 0; ks < 8; ++ks)
            bf[ct][ks] = *(const bf16x8*)&sB[(((cg * 4 + ct) * 8 + ks) * 64 + lane) * 8];

    float bias[4];
    #pragma unroll
    for (int ct = 0; ct < 4; ++ct) bias[ct] = b[cg * 64 + ct * 16 + c15];

    const int ntiles = (n + 31) >> 5;
    for (int tile = blockIdx.x; tile < ntiles; tile += gridDim.x) {
        const int base = tile * 32;
        const int row = base + ms * 16 + c15;
        bf16x8 af[8];
        #pragma unroll
        for (int ks = 0; ks < 8; ++ks) {
            bf16x8 a = {0, 0, 0, 0, 0, 0, 0, 0};
            if (row < n) {
                int karr = ks * 32 + g * 8;
                const unsigned short* p = (ks < 4)
                    ? &agg[(size_t)row * FEAT + karr]
                    : &xb[(size_t)row * FEAT + (karr - 128)];
                a = *(const bf16x8*)p;
            }
            af[ks] = a;
        }
        f32x4 z = {0.f, 0.f, 0.f, 0.f};
        f32x4 acc[4] = {z, z, z, z};
        #pragma unroll
        for (int ks = 0; ks < 8; ++ks)
            #pragma unroll
            for (int ct = 0; ct < 4; ++ct)
                acc[ct] = __builtin_amdgcn_mfma_f32_16x16x32_bf16(
                    af[ks], bf[ct][ks], acc[ct], 0, 0, 0);
        #pragma unroll
        for (int ct = 0; ct < 4; ++ct) {
            const int col = cg * 64 + ct * 16 + c15;
            #pragma unroll
            for (int r = 0; r < 4; ++r) {
                int node = base + ms * 16 + g * 4 + r;
                if (node < n) {
                    float v = fmaxf(acc[ct][r] + bias[ct], 0.f);
                    hb[(size_t)node * FEAT + col] = (unsigned short)f2bf_rne(v);
                }
            }
        }
    }
}

// ---------------------------------------------------------------------------
// y2 = hb @ W2l (MFMA), N=64, K=128, bf16 out (no bias).
__global__ __launch_bounds__(256, 2) void gemmy2_kernel(
    const unsigned short* __restrict__ hb, const float* __restrict__ Wl,
    unsigned short* __restrict__ y2, int n) {
    __shared__ __align__(16) unsigned short sB[128 * OUTF];   // 16 KB
    const int tid = threadIdx.x;

    for (int idx = tid; idx < 128 * OUTF; idx += 256) {
        int k = idx >> 6, col = idx & 63;
        float w = Wl[k * OUTF + col];
        int pos = ((col >> 4) * 4 + (k >> 5)) * 512
                + ((((k >> 3) & 3) * 16 + (col & 15)) * 8) + (k & 7);
        sB[pos] = (unsigned short)f2bf_rne(w);
    }
    __syncthreads();

    const int wv = tid >> 6, lane = tid & 63;
    const int g = lane >> 4, c15 = lane & 15;

    bf16x8 bf[4][4];
    #pragma unroll
    for (int ct = 0; ct < 4; ++ct)
        #pragma unroll
        for (int ks = 0; ks < 4; ++ks)
            bf[ct][ks] = *(const bf16x8*)&sB[((ct * 4 + ks) * 64 + lane) * 8];

    const int ntiles = (n + 63) >> 6;
    for (int tile = blockIdx.x; tile < ntiles; tile += gridDim.x) {
        const int base = tile * 64;
        const int row = base + wv * 16 + c15;
        bf16x8 af[4];
        #pragma unroll
        for (int ks = 0; ks < 4; ++ks) {
            bf16x8 a = {0, 0, 0, 0, 0, 0, 0, 0};
            if (row < n) a = *(const bf16x8*)&hb[(size_t)row * FEAT + ks * 32 + g * 8];
            af[ks] = a;
        }
        f32x4 z = {0.f, 0.f, 0.f, 0.f};
        f32x4 acc[4] = {z, z, z, z};
        #pragma unroll
        for (int ks = 0; ks < 4; ++ks)
            #pragma unroll
            for (int ct = 0; ct < 4; ++ct)
                acc[ct] = __builtin_amdgcn_mfma_f32_16x16x32_bf16(
                    af[ks], bf[ct][ks], acc[ct], 0, 0, 0);
        #pragma unroll
        for (int ct = 0; ct < 4; ++ct) {
            const int col = ct * 16 + c15;
            #pragma unroll
            for (int r = 0; r < 4; ++r) {
                int node = base + wv * 16 + g * 4 + r;
                if (node < n)
                    y2[(size_t)node * OUTF + col] = (unsigned short)f2bf_rne(acc[ct][r]);
            }
        }
    }
}

// ---------------------------------------------------------------------------
// GEMM2b (MFMA) + softmax: out = softmax(hb@W2r + meanY2 + b2), N=64, K=128.
__global__ __launch_bounds__(256, 2) void gemm2b_kernel(
    const unsigned short* __restrict__ hb, const unsigned short* __restrict__ aggy,
    const float* __restrict__ Wr, const float* __restrict__ b,
    float* __restrict__ out, int n) {
    __shared__ __align__(16) unsigned short sB[128 * OUTF];   // 16 KB
    const int tid = threadIdx.x;

    for (int idx = tid; idx < 128 * OUTF; idx += 256) {
        int k = idx >> 6, col = idx & 63;
        float w = Wr[k * OUTF + col];
        int pos = ((col >> 4) * 4 + (k >> 5)) * 512
                + ((((k >> 3) & 3) * 16 + (col & 15)) * 8) + (k & 7);
        sB[pos] = (unsigned short)f2bf_rne(w);
    }
    __syncthreads();

    const int wv = tid >> 6, lane = tid & 63;
    const int g = lane >> 4, c15 = lane & 15;

    bf16x8 bf[4][4];
    #pragma unroll
    for (int ct = 0; ct < 4; ++ct)
        #pragma unroll
        for (int ks = 0; ks < 4; ++ks)
            bf[ct][ks] = *(const bf16x8*)&sB[((ct * 4 + ks) * 64 + lane) * 8];

    float bias[4];
    #pragma unroll
    for (int ct = 0; ct < 4; ++ct) bias[ct] = b[ct * 16 + c15];

    const int ntiles = (n + 63) >> 6;
    for (int tile = blockIdx.x; tile < ntiles; tile += gridDim.x) {
        const int base = tile * 64;
        const int row = base + wv * 16 + c15;
        bf16x8 af[4];
        #pragma unroll
        for (int ks = 0; ks < 4; ++ks) {
            bf16x8 a = {0, 0, 0, 0, 0, 0, 0, 0};
            if (row < n) a = *(const bf16x8*)&hb[(size_t)row * FEAT + ks * 32 + g * 8];
            af[ks] = a;
        }
        f32x4 z = {0.f, 0.f, 0.f, 0.f};
        f32x4 acc[4] = {z, z, z, z};
        #pragma unroll
        for (int ks = 0; ks < 4; ++ks)
            #pragma unroll
            for (int ct = 0; ct < 4; ++ct)
                acc[ct] = __builtin_amdgcn_mfma_f32_16x16x32_bf16(
                    af[ks], bf[ct][ks], acc[ct], 0, 0, 0);

        #pragma unroll
        for (int r = 0; r < 4; ++r) {
            int node = base + wv * 16 + g * 4 + r;
            bool ok = node < n;
            float v[4];
            #pragma unroll
            for (int ct = 0; ct < 4; ++ct) {
                float my = 0.f;
                if (ok) {
                    unsigned short u = aggy[(size_t)node * OUTF + ct * 16 + c15];
                    my = __uint_as_float((unsigned)u << 16);
                }
                v[ct] = acc[ct][r] + bias[ct] + my;
            }
            float m = fmaxf(fmaxf(v[0], v[1]), fmaxf(v[2], v[3]));
            #pragma unroll
            for (int off = 8; off > 0; off >>= 1)
                m = fmaxf(m, __shfl_xor(m, off, 64));
            float e0 = __expf(v[0] - m), e1 = __expf(v[1] - m);
            float e2 = __expf(v[2] - m), e3 = __expf(v[3] - m);
            float s = e0 + e1 + e2 + e3;
            #pragma unroll
            for (int off = 8; off > 0; off >>= 1)
                s += __shfl_xor(s, off, 64);
            float inv = 1.0f / s;
            if (ok) {
                out[(size_t)node * OUTF + c15]      = e0 * inv;
                out[(size_t)node * OUTF + 16 + c15] = e1 * inv;
                out[(size_t)node * OUTF + 32 + c15] = e2 * inv;
                out[(size_t)node * OUTF + 48 + c15] = e3 * inv;
            }
        }
    }
}

// ---------------------------------------------------------------------------
extern "C" void kernel_launch(void* const* d_in, const int* in_sizes, int n_in,
                              void* d_out, int out_size, void* d_ws, size_t ws_size,
                              hipStream_t stream) {
    const float* x   = (const float*)d_in[0];
    const float* W1l = (const float*)d_in[1];
    const float* W1r = (const float*)d_in[2];
    const float* b1  = (const float*)d_in[3];
    const float* W2l = (const float*)d_in[4];
    const float* W2r = (const float*)d_in[5];
    const float* b2  = (const float*)d_in[6];
    const void*  ei1 = d_in[7];
    const void*  ei2 = d_in[8];
    float* out = (float*)d_out;

    const int n  = in_sizes[0] / FEAT;   // 100000
    const int e1 = in_sizes[7] / 2;      // 1600000
    const int e2 = in_sizes[8] / 2;
    const int emax = (e1 > e2) ? e1 : e2;

    const int nb = (n + BNODES - 1) >> BSH;                // 196 buckets
    if (nb > NBMAX) return;
    unsigned cap = (unsigned)(emax / nb + emax / (4 * nb) + 512);
    cap = (cap + 63u) & ~63u;                              // ~10752

    // Workspace: [flag 256B][xb 25.6M][hb 25.6M][aggregion 25.6M (pairs1|pairs2
    // alias pre-gather; then agg/y2/aggy)][cnt1 cnt2][rps1 rpe1 rps2 rpe2]
    // [esrc1][esrc2][pad]  ~= 96 MB
    char* ws = (char*)d_ws;
    const size_t fBytes   = (size_t)n * FEAT * 2;          // 25.6 MB
    const size_t cntBytes = ((size_t)NBMAX * 4 + 255) & ~(size_t)255;
    const size_t rpBytes  = (((size_t)n * 4) + 255) & ~(size_t)255;
    const size_t bktBytes = (((size_t)nb * cap * 4) + 255) & ~(size_t)255;  // ~8.4 MB
    if (2 * bktBytes > fBytes) return;   // pairs must fit in agg region
    unsigned*       flag = (unsigned*)ws;
    unsigned short* xb   = (unsigned short*)(ws + 256);
    unsigned short* hb   = (unsigned short*)(ws + 256 + fBytes);
    char*           aggr = ws + 256 + 2 * fBytes;
    unsigned short* agg  = (unsigned short*)aggr;
    unsigned short* y2   = agg;                         // reused after gemm1
    unsigned short* aggy = agg + (size_t)n * OUTF;      // second half of agg region
    unsigned* pairs1 = (unsigned*)aggr;                 // alias: dead before gather128
    unsigned* pairs2 = (unsigned*)(aggr + bktBytes);
    char* p = ws + 256 + 3 * fBytes;
    unsigned* cnt1 = (unsigned*)p;            p += cntBytes;
    unsigned* cnt2 = (unsigned*)p;            p += cntBytes;
    unsigned* rps1 = (unsigned*)p;            p += rpBytes;
    unsigned* rpe1 = (unsigned*)p;            p += rpBytes;
    unsigned* rps2 = (unsigned*)p;            p += rpBytes;
    unsigned* rpe2 = (unsigned*)p;            p += rpBytes;
    int*      esrc1 = (int*)p;                p += bktBytes;
    int*      esrc2 = (int*)p;                p += bktBytes;
    p += 256;
    if ((size_t)(p - ws) > ws_size) return;

    hipMemsetAsync(flag, 0, 4, stream);
    detect_idx_kernel<<<1, 256, 0, stream>>>((const unsigned*)ei1, flag);
    convert_kernel<<<2048, 256, 0, stream>>>(x, xb, in_sizes[0] / 4);

    const int gatherGrid = (n + 3) / 4;       // one node per wave, 4 waves/block

    // ---- dual CSR build (both layers, 2 dispatches) ----
    init_cnt2_kernel<<<(nb + 255) / 256, 256, 0, stream>>>(cnt1, cnt2, cap, nb);
    bucket2_kernel<<<2 * BUCKET_BLOCKS, 256, 0, stream>>>(
        ei1, ei2, pairs1, pairs2, cnt1, cnt2, flag, e1, e2, cap, nb);
    csr2_kernel<<<2 * nb, 256, 0, stream>>>(
        pairs1, pairs2, cnt1, cnt2, rps1, rpe1, rps2, rpe2, esrc1, esrc2, cap, n, nb);

    // ---- layer 1 ----
    gather_mean128_kernel<<<gatherGrid, 256, 0, stream>>>((const uint4*)xb, rps1, rpe1,
                                                          esrc1, (uint4*)agg, n);
    gemm1_kernel<<<640, 256, 0, stream>>>(agg, xb, W1l, W1r, b1, hb, n);

    // ---- layer 2 ----
    gemmy2_kernel<<<512, 256, 0, stream>>>(hb, W2l, y2, n);
    gather_mean64_kernel<<<gatherGrid, 256, 0, stream>>>((const uint4*)y2, rps2, rpe2,
                                                         esrc2, (uint4*)aggy, n);
    gemm2b_kernel<<<512, 256, 0, stream>>>(hb, aggy, W2r, b2, out, n);
}

// Round 17
// 256.013 us; speedup vs baseline: 1.0046x; 1.0040x over previous
//
#include <hip/hip_runtime.h>

// GraphSAGE 2-layer, bf16 feature plane + MFMA GEMMs + fused dual-CSR build.
// R17: single change vs validated R16 = STAGE 2048->4096 in bucket2 (16
// register-staged edges/thread), halving per-block barrier/scan overhead.
// Gathers keep v_dot2_f32_bf16 (validated R16).
// N=100000, E=1600000, IN=HID=128, OUT=64; edge_index int32 or int64.

#define FEAT 128
#define OUTF 64
#define BSH 9                   // 512 nodes per bucket
#define BNODES 512
#define NBMAX 256               // max buckets
#define BUCKET_BLOCKS 512       // blocks per edge-set in bucket2
#define STAGE 4096              // edges sorted+flushed per stage (16/thread)

typedef __attribute__((ext_vector_type(8))) short bf16x8;
typedef __attribute__((ext_vector_type(4))) float f32x4;

__device__ __forceinline__ unsigned f2bf_rne(float f) {
    unsigned u = __float_as_uint(f);
    return (u + 0x7fffu + ((u >> 16) & 1u)) >> 16;
}

// acc += selected bf16 half of u (sel = packed v2bf16 (1,0) or (0,1)).
__device__ __forceinline__ void d2acc(float& a, unsigned u, unsigned sel) {
    asm("v_dot2_f32_bf16 %0, %1, %2, %0" : "+v"(a) : "v"(u), "v"(sel));
}
#define ACC8(v)                                                              \
    d2acc(a0, (v).x, selLo); d2acc(a1, (v).x, selHi);                        \
    d2acc(a2, (v).y, selLo); d2acc(a3, (v).y, selHi);                        \
    d2acc(a4, (v).z, selLo); d2acc(a5, (v).z, selHi);                        \
    d2acc(a6, (v).w, selLo); d2acc(a7, (v).w, selHi);

// ---------------------------------------------------------------------------
// int64 vs int32 detection: indices < 100000 so int64 => odd 32-bit words all 0.
__global__ void detect_idx_kernel(const unsigned* __restrict__ ei, unsigned* __restrict__ flag) {
    unsigned v = ei[2 * threadIdx.x + 1];
    if (v != 0u) atomicOr(flag, 1u);
}

// ---------------------------------------------------------------------------
__global__ __launch_bounds__(256) void convert_kernel(
    const float* __restrict__ in, unsigned short* __restrict__ outb, int total4) {
    for (int i = blockIdx.x * 256 + threadIdx.x; i < total4; i += gridDim.x * 256) {
        float4 v = *(const float4*)&in[(size_t)i * 4];
        ushort4 o;
        o.x = (unsigned short)f2bf_rne(v.x);
        o.y = (unsigned short)f2bf_rne(v.y);
        o.z = (unsigned short)f2bf_rne(v.z);
        o.w = (unsigned short)f2bf_rne(v.w);
        *(ushort4*)&outb[(size_t)i * 4] = o;
    }
}

// ---------------------------------------------------------------------------
__global__ __launch_bounds__(256) void init_cnt2_kernel(
    unsigned* __restrict__ cnt1, unsigned* __restrict__ cnt2, unsigned cap, int nb) {
    int i = blockIdx.x * 256 + threadIdx.x;
    if (i < nb) { cnt1[i] = (unsigned)i * cap; cnt2[i] = (unsigned)i * cap; }
}

// ---------------------------------------------------------------------------
// Dual bucket scatter with LDS stage-sort + coalesced flush.
__global__ __launch_bounds__(256) void bucket2_kernel(
    const void* __restrict__ ei1_raw, const void* __restrict__ ei2_raw,
    unsigned* __restrict__ pairs1, unsigned* __restrict__ pairs2,
    unsigned* __restrict__ cnt1, unsigned* __restrict__ cnt2,
    const unsigned* __restrict__ flag, int e1, int e2, unsigned cap, int nb) {
    __shared__ unsigned hist[NBMAX];    // whole-chunk totals
    __shared__ unsigned wcur[NBMAX];    // global write cursor per bucket
    __shared__ unsigned lhist[NBMAX];   // per-stage hist
    __shared__ unsigned lseg[NBMAX];    // per-stage exclusive scan
    __shared__ unsigned loffs[NBMAX];   // per-stage scatter cursor
    __shared__ unsigned sorted[STAGE];
    __shared__ unsigned char sbid[STAGE];
    __shared__ unsigned wsum[2];
    const int tid = threadIdx.x;
    const int lane = tid & 63;
    const bool is32 = (*flag != 0u);
    const int side = blockIdx.x / BUCKET_BLOCKS;
    const int bid = blockIdx.x % BUCKET_BLOCKS;
    const void* ei_raw = side ? ei2_raw : ei1_raw;
    unsigned* pairs = side ? pairs2 : pairs1;
    unsigned* cnt = side ? cnt2 : cnt1;
    const int nedge = side ? e2 : e1;
    const int chunk = (nedge + BUCKET_BLOCKS - 1) / BUCKET_BLOCKS;
    const int e0 = bid * chunk;
    const int eEnd = min(e0 + chunk, nedge);
    if (e0 >= nedge) return;

    // phase 1: whole-chunk histogram
    for (int i = tid; i < nb; i += 256) hist[i] = 0u;
    __syncthreads();
    for (int e = e0 + tid; e < eEnd; e += 256) {
        int dst = is32 ? ((const int*)ei_raw)[nedge + e]
                       : (int)((const long long*)ei_raw)[nedge + e];
        atomicAdd(&hist[(unsigned)dst >> BSH], 1u);
    }
    __syncthreads();
    // phase 2: one reservation per bucket
    for (int i = tid; i < nb; i += 256) {
        unsigned c = hist[i];
        wcur[i] = c ? atomicAdd(&cnt[i], c) : 0u;
    }
    __syncthreads();

    // phase 3: staged sort + coalesced flush (16 edges/thread/stage)
    for (int s0 = e0; s0 < eEnd; s0 += STAGE) {
        const int sEnd = min(s0 + STAGE, eEnd);
        const int cs = sEnd - s0;
        for (int i = tid; i < NBMAX; i += 256) lhist[i] = 0u;
        __syncthreads();
        unsigned myp[16];
        unsigned myb[16];
        bool myv[16];
        #pragma unroll
        for (int k = 0; k < 16; ++k) {
            int e = s0 + k * 256 + tid;
            bool valid = e < sEnd;
            myv[k] = valid;
            int src = 0, dst = 0;
            if (valid) {
                if (is32) {
                    const int* ei = (const int*)ei_raw;
                    src = ei[e]; dst = ei[nedge + e];
                } else {
                    const long long* ei = (const long long*)ei_raw;
                    src = (int)ei[e]; dst = (int)ei[nedge + e];
                }
            }
            unsigned b = (unsigned)dst >> BSH;
            myp[k] = (((unsigned)dst & (BNODES - 1u)) << 17) | (unsigned)src;
            myb[k] = b;
            if (valid) atomicAdd(&lhist[b], 1u);
        }
        __syncthreads();
        // wave-parallel exclusive scan over 256 slots: threads 0..127, 2 each
        unsigned incl = 0, tsum = 0, sv0 = 0;
        if (tid < 128) {
            sv0 = lhist[2 * tid];
            unsigned sv1 = lhist[2 * tid + 1];
            tsum = sv0 + sv1;
            incl = tsum;
            #pragma unroll
            for (int off = 1; off < 64; off <<= 1) {
                unsigned t = __shfl_up(incl, off, 64);
                if (lane >= off) incl += t;
            }
            if (lane == 63) wsum[tid >> 6] = incl;
        }
        __syncthreads();
        if (tid < 128) {
            unsigned pre = (tid >> 6 ? wsum[0] : 0u) + incl - tsum;
            lseg[2 * tid] = pre;
            lseg[2 * tid + 1] = pre + sv0;
            loffs[2 * tid] = pre;
            loffs[2 * tid + 1] = pre + sv0;
        }
        __syncthreads();
        #pragma unroll
        for (int k = 0; k < 16; ++k) {
            if (myv[k]) {
                unsigned p = atomicAdd(&loffs[myb[k]], 1u);
                sorted[p] = myp[k];
                sbid[p] = (unsigned char)myb[k];
            }
        }
        __syncthreads();
        for (int i = tid; i < cs; i += 256) {
            unsigned b = sbid[i];
            unsigned pos = wcur[b] + ((unsigned)i - lseg[b]);
            if (pos < (b + 1u) * cap)
                pairs[pos] = sorted[i];
        }
        __syncthreads();
        for (int i = tid; i < nb; i += 256) wcur[i] += lhist[i];
        __syncthreads();
    }
}

// ---------------------------------------------------------------------------
// Dual per-bucket counting sort over 512-node buckets.
__global__ __launch_bounds__(256) void csr2_kernel(
    const unsigned* __restrict__ pairs1, const unsigned* __restrict__ pairs2,
    const unsigned* __restrict__ cnt1, const unsigned* __restrict__ cnt2,
    unsigned* __restrict__ rps1, unsigned* __restrict__ rpe1,
    unsigned* __restrict__ rps2, unsigned* __restrict__ rpe2,
    int* __restrict__ esrc1, int* __restrict__ esrc2,
    unsigned cap, int n, int nb) {
    __shared__ unsigned hist[BNODES], excl[BNODES], offs[BNODES];
    __shared__ unsigned wsum[4], woff[4];
    const int side = blockIdx.x / nb;
    const int b = blockIdx.x % nb;
    const unsigned* pairs = side ? pairs2 : pairs1;
    const unsigned* cnt = side ? cnt2 : cnt1;
    unsigned* rps = side ? rps2 : rps1;
    unsigned* rpe = side ? rpe2 : rpe1;
    int* esrc = side ? esrc2 : esrc1;
    const int tid = threadIdx.x;
    const int lane = tid & 63;
    const unsigned base = (unsigned)b * cap;
    unsigned count = cnt[b] - base;
    if (count > cap) count = cap;

    hist[tid] = 0u; hist[tid + 256] = 0u;
    __syncthreads();
    for (unsigned e = tid; e < count; e += 256)
        atomicAdd(&hist[pairs[base + e] >> 17], 1u);
    __syncthreads();
    // wave-parallel exclusive scan of hist[0..512): thread t owns entries 2t,2t+1
    {
        unsigned s0 = hist[2 * tid], s1 = hist[2 * tid + 1];
        unsigned tsum = s0 + s1;
        unsigned incl = tsum;
        #pragma unroll
        for (int off = 1; off < 64; off <<= 1) {
            unsigned t = __shfl_up(incl, off, 64);
            if (lane >= off) incl += t;
        }
        if (lane == 63) wsum[tid >> 6] = incl;
        __syncthreads();
        if (tid == 0) {
            unsigned s = 0;
            #pragma unroll
            for (int w = 0; w < 4; ++w) { unsigned t = wsum[w]; woff[w] = s; s += t; }
        }
        __syncthreads();
        unsigned pre = woff[tid >> 6] + incl - tsum;
        excl[2 * tid] = pre;
        excl[2 * tid + 1] = pre + s0;
    }
    __syncthreads();
    #pragma unroll
    for (int h = 0; h < 2; ++h) {
        int lt = tid + h * 256;
        int node = b * BNODES + lt;
        if (node < n) {
            rps[node] = base + excl[lt];
            rpe[node] = base + excl[lt] + hist[lt];
        }
        offs[lt] = excl[lt];
    }
    __syncthreads();
    for (unsigned e = tid; e < count; e += 256) {
        unsigned p = pairs[base + e];
        unsigned lpos = atomicAdd(&offs[p >> 17], 1u);
        esrc[base + lpos] = (int)(p & 0x1FFFFu);
    }
}

// ---------------------------------------------------------------------------
// Mean-gather, 128-wide bf16 rows. Row = 16 lanes x 16B; 4 edges per load
// instruction; 16-edge main step keeps 4KB/wave in flight. dot2 accumulate.
__global__ __launch_bounds__(256) void gather_mean128_kernel(
    const uint4* __restrict__ featq, const unsigned* __restrict__ rps,
    const unsigned* __restrict__ rpe, const int* __restrict__ esrc,
    uint4* __restrict__ aggq, int n) {
    const int wave = threadIdx.x >> 6;
    const int lane = threadIdx.x & 63;
    const int qi = lane >> 4;     // edge slot 0..3
    const int li = lane & 15;     // 16B block within row
    const unsigned selLo = 0x00003F80u;   // v2bf16 (1,0)
    const unsigned selHi = 0x3F800000u;   // v2bf16 (0,1)
    for (int node = blockIdx.x * 4 + wave; node < n; node += gridDim.x * 4) {
        unsigned rs = rps[node];
        unsigned re = rpe[node];
        float a0 = 0.f, a1 = 0.f, a2 = 0.f, a3 = 0.f;
        float a4 = 0.f, a5 = 0.f, a6 = 0.f, a7 = 0.f;
        unsigned j = rs;
        for (; j + 16 <= re; j += 16) {
            unsigned i0 = (unsigned)esrc[j + qi] * 16u + (unsigned)li;
            unsigned i1 = (unsigned)esrc[j + 4 + qi] * 16u + (unsigned)li;
            unsigned i2 = (unsigned)esrc[j + 8 + qi] * 16u + (unsigned)li;
            unsigned i3 = (unsigned)esrc[j + 12 + qi] * 16u + (unsigned)li;
            uint4 v0 = featq[i0];
            uint4 v1 = featq[i1];
            uint4 v2 = featq[i2];
            uint4 v3 = featq[i3];
            ACC8(v0); ACC8(v1); ACC8(v2); ACC8(v3);
        }
        for (; j + 8 <= re; j += 8) {
            unsigned i0 = (unsigned)esrc[j + qi] * 16u + (unsigned)li;
            unsigned i1 = (unsigned)esrc[j + 4 + qi] * 16u + (unsigned)li;
            uint4 v0 = featq[i0];
            uint4 v1 = featq[i1];
            ACC8(v0); ACC8(v1);
        }
        for (; j + 4 <= re; j += 4) {
            unsigned i0 = (unsigned)esrc[j + qi] * 16u + (unsigned)li;
            uint4 v0 = featq[i0];
            ACC8(v0);
        }
        unsigned rem = re - j;
        if ((unsigned)qi < rem) {
            unsigned i0 = (unsigned)esrc[j + qi] * 16u + (unsigned)li;
            uint4 v0 = featq[i0];
            ACC8(v0);
        }
        a0 += __shfl_xor(a0, 16, 64); a1 += __shfl_xor(a1, 16, 64);
        a2 += __shfl_xor(a2, 16, 64); a3 += __shfl_xor(a3, 16, 64);
        a4 += __shfl_xor(a4, 16, 64); a5 += __shfl_xor(a5, 16, 64);
        a6 += __shfl_xor(a6, 16, 64); a7 += __shfl_xor(a7, 16, 64);
        a0 += __shfl_xor(a0, 32, 64); a1 += __shfl_xor(a1, 32, 64);
        a2 += __shfl_xor(a2, 32, 64); a3 += __shfl_xor(a3, 32, 64);
        a4 += __shfl_xor(a4, 32, 64); a5 += __shfl_xor(a5, 32, 64);
        a6 += __shfl_xor(a6, 32, 64); a7 += __shfl_xor(a7, 32, 64);
        if (lane < 16) {
            float inv = (re > rs) ? 1.0f / (float)(re - rs) : 0.0f;
            uint4 o;
            o.x = f2bf_rne(a0 * inv) | (f2bf_rne(a1 * inv) << 16);
            o.y = f2bf_rne(a2 * inv) | (f2bf_rne(a3 * inv) << 16);
            o.z = f2bf_rne(a4 * inv) | (f2bf_rne(a5 * inv) << 16);
            o.w = f2bf_rne(a6 * inv) | (f2bf_rne(a7 * inv) << 16);
            aggq[(size_t)node * 16 + lane] = o;
        }
    }
}

// ---------------------------------------------------------------------------
// Mean-gather, 64-wide bf16 rows (y2). Row = 8 lanes x 16B; 8 edges per load.
__global__ __launch_bounds__(256) void gather_mean64_kernel(
    const uint4* __restrict__ y2q, const unsigned* __restrict__ rps,
    const unsigned* __restrict__ rpe, const int* __restrict__ esrc,
    uint4* __restrict__ aggyq, int n) {
    const int wave = threadIdx.x >> 6;
    const int lane = threadIdx.x & 63;
    const int oi = lane >> 3;     // edge slot 0..7
    const int li = lane & 7;      // 16B block within row
    const unsigned selLo = 0x00003F80u;
    const unsigned selHi = 0x3F800000u;
    for (int node = blockIdx.x * 4 + wave; node < n; node += gridDim.x * 4) {
        unsigned rs = rps[node];
        unsigned re = rpe[node];
        float a0 = 0.f, a1 = 0.f, a2 = 0.f, a3 = 0.f;
        float a4 = 0.f, a5 = 0.f, a6 = 0.f, a7 = 0.f;
        unsigned j = rs;
        for (; j + 16 <= re; j += 16) {
            unsigned i0 = (unsigned)esrc[j + oi] * 8u + (unsigned)li;
            unsigned i1 = (unsigned)esrc[j + 8 + oi] * 8u + (unsigned)li;
            uint4 v0 = y2q[i0];
            uint4 v1 = y2q[i1];
            ACC8(v0); ACC8(v1);
        }
        for (; j + 8 <= re; j += 8) {
            unsigned i0 = (unsigned)esrc[j + oi] * 8u + (unsigned)li;
            uint4 v0 = y2q[i0];
            ACC8(v0);
        }
        unsigned rem = re - j;
        if ((unsigned)oi < rem) {
            unsigned i0 = (unsigned)esrc[j + oi] * 8u + (unsigned)li;
            uint4 v0 = y2q[i0];
            ACC8(v0);
        }
        a0 += __shfl_xor(a0, 8, 64);  a1 += __shfl_xor(a1, 8, 64);
        a2 += __shfl_xor(a2, 8, 64);  a3 += __shfl_xor(a3, 8, 64);
        a4 += __shfl_xor(a4, 8, 64);  a5 += __shfl_xor(a5, 8, 64);
        a6 += __shfl_xor(a6, 8, 64);  a7 += __shfl_xor(a7, 8, 64);
        a0 += __shfl_xor(a0, 16, 64); a1 += __shfl_xor(a1, 16, 64);
        a2 += __shfl_xor(a2, 16, 64); a3 += __shfl_xor(a3, 16, 64);
        a4 += __shfl_xor(a4, 16, 64); a5 += __shfl_xor(a5, 16, 64);
        a6 += __shfl_xor(a6, 16, 64); a7 += __shfl_xor(a7, 16, 64);
        a0 += __shfl_xor(a0, 32, 64); a1 += __shfl_xor(a1, 32, 64);
        a2 += __shfl_xor(a2, 32, 64); a3 += __shfl_xor(a3, 32, 64);
        a4 += __shfl_xor(a4, 32, 64); a5 += __shfl_xor(a5, 32, 64);
        a6 += __shfl_xor(a6, 32, 64); a7 += __shfl_xor(a7, 32, 64);
        if (lane < 8) {
            float inv = (re > rs) ? 1.0f / (float)(re - rs) : 0.0f;
            uint4 o;
            o.x = f2bf_rne(a0 * inv) | (f2bf_rne(a1 * inv) << 16);
            o.y = f2bf_rne(a2 * inv) | (f2bf_rne(a3 * inv) << 16);
            o.z = f2bf_rne(a4 * inv) | (f2bf_rne(a5 * inv) << 16);
            o.w = f2bf_rne(a6 * inv) | (f2bf_rne(a7 * inv) << 16);
            aggyq[(size_t)node * 8 + lane] = o;
        }
    }
}

// ---------------------------------------------------------------------------
// GEMM1 (MFMA): hb = relu([agg|xb] @ [W1l;W1r] + b1), N=128, K=256, bf16 out.
__global__ __launch_bounds__(256, 2) void gemm1_kernel(
    const unsigned short* __restrict__ agg, const unsigned short* __restrict__ xb,
    const float* __restrict__ Wl, const float* __restrict__ Wr,
    const float* __restrict__ b, unsigned short* __restrict__ hb, int n) {
    __shared__ __align__(16) unsigned short sB[256 * FEAT];   // 64 KB
    const int tid = threadIdx.x;

    for (int idx = tid; idx < 256 * FEAT; idx += 256) {
        int k = idx >> 7, col = idx & 127;
        float w = (k < 128) ? Wl[k * FEAT + col] : Wr[(k - 128) * FEAT + col];
        int pos = ((col >> 4) * 8 + (k >> 5)) * 512
                + ((((k >> 3) & 3) * 16 + (col & 15)) * 8) + (k & 7);
        sB[pos] = (unsigned short)f2bf_rne(w);
    }
    __syncthreads();

    const int wv = tid >> 6, lane = tid & 63;
    const int cg = wv & 1;
    const int ms = wv >> 1;
    const int g = lane >> 4, c15 = lane & 15;

    bf16x8 bf[4][8];
    #pragma unroll
    for (int ct = 0; ct < 4; ++ct)
        #pragma unroll
        for (int ks = 0; ks < 8; ++ks)
            bf[ct][ks] = *(const bf16x8*)&sB[(((cg * 4 + ct) * 8 + ks) * 64 + lane) * 8];

    float bias[4];
    #pragma unroll
    for (int ct = 0; ct < 4; ++ct) bias[ct] = b[cg * 64 + ct * 16 + c15];

    const int ntiles = (n + 31) >> 5;
    for (int tile = blockIdx.x; tile < ntiles; tile += gridDim.x) {
        const int base = tile * 32;
        const int row = base + ms * 16 + c15;
        bf16x8 af[8];
        #pragma unroll
        for (int ks = 0; ks < 8; ++ks) {
            bf16x8 a = {0, 0, 0, 0, 0, 0, 0, 0};
            if (row < n) {
                int karr = ks * 32 + g * 8;
                const unsigned short* p = (ks < 4)
                    ? &agg[(size_t)row * FEAT + karr]
                    : &xb[(size_t)row * FEAT + (karr - 128)];
                a = *(const bf16x8*)p;
            }
            af[ks] = a;
        }
        f32x4 z = {0.f, 0.f, 0.f, 0.f};
        f32x4 acc[4] = {z, z, z, z};
        #pragma unroll
        for (int ks = 0; ks < 8; ++ks)
            #pragma unroll
            for (int ct = 0; ct < 4; ++ct)
                acc[ct] = __builtin_amdgcn_mfma_f32_16x16x32_bf16(
                    af[ks], bf[ct][ks], acc[ct], 0, 0, 0);
        #pragma unroll
        for (int ct = 0; ct < 4; ++ct) {
            const int col = cg * 64 + ct * 16 + c15;
            #pragma unroll
            for (int r = 0; r < 4; ++r) {
                int node = base + ms * 16 + g * 4 + r;
                if (node < n) {
                    float v = fmaxf(acc[ct][r] + bias[ct], 0.f);
                    hb[(size_t)node * FEAT + col] = (unsigned short)f2bf_rne(v);
                }
            }
        }
    }
}

// ---------------------------------------------------------------------------
// y2 = hb @ W2l (MFMA), N=64, K=128, bf16 out (no bias).
__global__ __launch_bounds__(256, 2) void gemmy2_kernel(
    const unsigned short* __restrict__ hb, const float* __restrict__ Wl,
    unsigned short* __restrict__ y2, int n) {
    __shared__ __align__(16) unsigned short sB[128 * OUTF];   // 16 KB
    const int tid = threadIdx.x;

    for (int idx = tid; idx < 128 * OUTF; idx += 256) {
        int k = idx >> 6, col = idx & 63;
        float w = Wl[k * OUTF + col];
        int pos = ((col >> 4) * 4 + (k >> 5)) * 512
                + ((((k >> 3) & 3) * 16 + (col & 15)) * 8) + (k & 7);
        sB[pos] = (unsigned short)f2bf_rne(w);
    }
    __syncthreads();

    const int wv = tid >> 6, lane = tid & 63;
    const int g = lane >> 4, c15 = lane & 15;

    bf16x8 bf[4][4];
    #pragma unroll
    for (int ct = 0; ct < 4; ++ct)
        #pragma unroll
        for (int ks = 0; ks < 4; ++ks)
            bf[ct][ks] = *(const bf16x8*)&sB[((ct * 4 + ks) * 64 + lane) * 8];

    const int ntiles = (n + 63) >> 6;
    for (int tile = blockIdx.x; tile < ntiles; tile += gridDim.x) {
        const int base = tile * 64;
        const int row = base + wv * 16 + c15;
        bf16x8 af[4];
        #pragma unroll
        for (int ks = 0; ks < 4; ++ks) {
            bf16x8 a = {0, 0, 0, 0, 0, 0, 0, 0};
            if (row < n) a = *(const bf16x8*)&hb[(size_t)row * FEAT + ks * 32 + g * 8];
            af[ks] = a;
        }
        f32x4 z = {0.f, 0.f, 0.f, 0.f};
        f32x4 acc[4] = {z, z, z, z};
        #pragma unroll
        for (int ks = 0; ks < 4; ++ks)
            #pragma unroll
            for (int ct = 0; ct < 4; ++ct)
                acc[ct] = __builtin_amdgcn_mfma_f32_16x16x32_bf16(
                    af[ks], bf[ct][ks], acc[ct], 0, 0, 0);
        #pragma unroll
        for (int ct = 0; ct < 4; ++ct) {
            const int col = ct * 16 + c15;
            #pragma unroll
            for (int r = 0; r < 4; ++r) {
                int node = base + wv * 16 + g * 4 + r;
                if (node < n)
                    y2[(size_t)node * OUTF + col] = (unsigned short)f2bf_rne(acc[ct][r]);
            }
        }
    }
}

// ---------------------------------------------------------------------------
// GEMM2b (MFMA) + softmax: out = softmax(hb@W2r + meanY2 + b2), N=64, K=128.
__global__ __launch_bounds__(256, 2) void gemm2b_kernel(
    const unsigned short* __restrict__ hb, const unsigned short* __restrict__ aggy,
    const float* __restrict__ Wr, const float* __restrict__ b,
    float* __restrict__ out, int n) {
    __shared__ __align__(16) unsigned short sB[128 * OUTF];   // 16 KB
    const int tid = threadIdx.x;

    for (int idx = tid; idx < 128 * OUTF; idx += 256) {
        int k = idx >> 6, col = idx & 63;
        float w = Wr[k * OUTF + col];
        int pos = ((col >> 4) * 4 + (k >> 5)) * 512
                + ((((k >> 3) & 3) * 16 + (col & 15)) * 8) + (k & 7);
        sB[pos] = (unsigned short)f2bf_rne(w);
    }
    __syncthreads();

    const int wv = tid >> 6, lane = tid & 63;
    const int g = lane >> 4, c15 = lane & 15;

    bf16x8 bf[4][4];
    #pragma unroll
    for (int ct = 0; ct < 4; ++ct)
        #pragma unroll
        for (int ks = 0; ks < 4; ++ks)
            bf[ct][ks] = *(const bf16x8*)&sB[((ct * 4 + ks) * 64 + lane) * 8];

    float bias[4];
    #pragma unroll
    for (int ct = 0; ct < 4; ++ct) bias[ct] = b[ct * 16 + c15];

    const int ntiles = (n + 63) >> 6;
    for (int tile = blockIdx.x; tile < ntiles; tile += gridDim.x) {
        const int base = tile * 64;
        const int row = base + wv * 16 + c15;
        bf16x8 af[4];
        #pragma unroll
        for (int ks = 0; ks < 4; ++ks) {
            bf16x8 a = {0, 0, 0, 0, 0, 0, 0, 0};
            if (row < n) a = *(const bf16x8*)&hb[(size_t)row * FEAT + ks * 32 + g * 8];
            af[ks] = a;
        }
        f32x4 z = {0.f, 0.f, 0.f, 0.f};
        f32x4 acc[4] = {z, z, z, z};
        #pragma unroll
        for (int ks = 0; ks < 4; ++ks)
            #pragma unroll
            for (int ct = 0; ct < 4; ++ct)
                acc[ct] = __builtin_amdgcn_mfma_f32_16x16x32_bf16(
                    af[ks], bf[ct][ks], acc[ct], 0, 0, 0);

        #pragma unroll
        for (int r = 0; r < 4; ++r) {
            int node = base + wv * 16 + g * 4 + r;
            bool ok = node < n;
            float v[4];
            #pragma unroll
            for (int ct = 0; ct < 4; ++ct) {
                float my = 0.f;
                if (ok) {
                    unsigned short u = aggy[(size_t)node * OUTF + ct * 16 + c15];
                    my = __uint_as_float((unsigned)u << 16);
                }
                v[ct] = acc[ct][r] + bias[ct] + my;
            }
            float m = fmaxf(fmaxf(v[0], v[1]), fmaxf(v[2], v[3]));
            #pragma unroll
            for (int off = 8; off > 0; off >>= 1)
                m = fmaxf(m, __shfl_xor(m, off, 64));
            float e0 = __expf(v[0] - m), e1 = __expf(v[1] - m);
            float e2 = __expf(v[2] - m), e3 = __expf(v[3] - m);
            float s = e0 + e1 + e2 + e3;
            #pragma unroll
            for (int off = 8; off > 0; off >>= 1)
                s += __shfl_xor(s, off, 64);
            float inv = 1.0f / s;
            if (ok) {
                out[(size_t)node * OUTF + c15]      = e0 * inv;
                out[(size_t)node * OUTF + 16 + c15] = e1 * inv;
                out[(size_t)node * OUTF + 32 + c15] = e2 * inv;
                out[(size_t)node * OUTF + 48 + c15] = e3 * inv;
            }
        }
    }
}

// ---------------------------------------------------------------------------
extern "C" void kernel_launch(void* const* d_in, const int* in_sizes, int n_in,
                              void* d_out, int out_size, void* d_ws, size_t ws_size,
                              hipStream_t stream) {
    const float* x   = (const float*)d_in[0];
    const float* W1l = (const float*)d_in[1];
    const float* W1r = (const float*)d_in[2];
    const float* b1  = (const float*)d_in[3];
    const float* W2l = (const float*)d_in[4];
    const float* W2r = (const float*)d_in[5];
    const float* b2  = (const float*)d_in[6];
    const void*  ei1 = d_in[7];
    const void*  ei2 = d_in[8];
    float* out = (float*)d_out;

    const int n  = in_sizes[0] / FEAT;   // 100000
    const int e1 = in_sizes[7] / 2;      // 1600000
    const int e2 = in_sizes[8] / 2;
    const int emax = (e1 > e2) ? e1 : e2;

    const int nb = (n + BNODES - 1) >> BSH;                // 196 buckets
    if (nb > NBMAX) return;
    unsigned cap = (unsigned)(emax / nb + emax / (4 * nb) + 512);
    cap = (cap + 63u) & ~63u;                              // ~10752

    // Workspace: [flag 256B][xb 25.6M][hb 25.6M][aggregion 25.6M (pairs1|pairs2
    // alias pre-gather; then agg/y2/aggy)][cnt1 cnt2][rps1 rpe1 rps2 rpe2]
    // [esrc1][esrc2][pad]  ~= 96 MB
    char* ws = (char*)d_ws;
    const size_t fBytes   = (size_t)n * FEAT * 2;          // 25.6 MB
    const size_t cntBytes = ((size_t)NBMAX * 4 + 255) & ~(size_t)255;
    const size_t rpBytes  = (((size_t)n * 4) + 255) & ~(size_t)255;
    const size_t bktBytes = (((size_t)nb * cap * 4) + 255) & ~(size_t)255;  // ~8.4 MB
    if (2 * bktBytes > fBytes) return;   // pairs must fit in agg region
    unsigned*       flag = (unsigned*)ws;
    unsigned short* xb   = (unsigned short*)(ws + 256);
    unsigned short* hb   = (unsigned short*)(ws + 256 + fBytes);
    char*           aggr = ws + 256 + 2 * fBytes;
    unsigned short* agg  = (unsigned short*)aggr;
    unsigned short* y2   = agg;                         // reused after gemm1
    unsigned short* aggy = agg + (size_t)n * OUTF;      // second half of agg region
    unsigned* pairs1 = (unsigned*)aggr;                 // alias: dead before gather128
    unsigned* pairs2 = (unsigned*)(aggr + bktBytes);
    char* p = ws + 256 + 3 * fBytes;
    unsigned* cnt1 = (unsigned*)p;            p += cntBytes;
    unsigned* cnt2 = (unsigned*)p;            p += cntBytes;
    unsigned* rps1 = (unsigned*)p;            p += rpBytes;
    unsigned* rpe1 = (unsigned*)p;            p += rpBytes;
    unsigned* rps2 = (unsigned*)p;            p += rpBytes;
    unsigned* rpe2 = (unsigned*)p;            p += rpBytes;
    int*      esrc1 = (int*)p;                p += bktBytes;
    int*      esrc2 = (int*)p;                p += bktBytes;
    p += 256;
    if ((size_t)(p - ws) > ws_size) return;

    hipMemsetAsync(flag, 0, 4, stream);
    detect_idx_kernel<<<1, 256, 0, stream>>>((const unsigned*)ei1, flag);
    convert_kernel<<<2048, 256, 0, stream>>>(x, xb, in_sizes[0] / 4);

    const int gatherGrid = (n + 3) / 4;       // one node per wave, 4 waves/block

    // ---- dual CSR build (both layers, 2 dispatches) ----
    init_cnt2_kernel<<<(nb + 255) / 256, 256, 0, stream>>>(cnt1, cnt2, cap, nb);
    bucket2_kernel<<<2 * BUCKET_BLOCKS, 256, 0, stream>>>(
        ei1, ei2, pairs1, pairs2, cnt1, cnt2, flag, e1, e2, cap, nb);
    csr2_kernel<<<2 * nb, 256, 0, stream>>>(
        pairs1, pairs2, cnt1, cnt2, rps1, rpe1, rps2, rpe2, esrc1, esrc2, cap, n, nb);

    // ---- layer 1 ----
    gather_mean128_kernel<<<gatherGrid, 256, 0, stream>>>((const uint4*)xb, rps1, rpe1,
                                                          esrc1, (uint4*)agg, n);
    gemm1_kernel<<<640, 256, 0, stream>>>(agg, xb, W1l, W1r, b1, hb, n);

    // ---- layer 2 ----
    gemmy2_kernel<<<512, 256, 0, stream>>>(hb, W2l, y2, n);
    gather_mean64_kernel<<<gatherGrid, 256, 0, stream>>>((const uint4*)y2, rps2, rpe2,
                                                         esrc2, (uint4*)aggy, n);
    gemm2b_kernel<<<512, 256, 0, stream>>>(hb, aggy, W2r, b2, out, n);
}